// Round 5
// baseline (666.264 us; speedup 1.0000x reference)
//
#include <hip/hip_runtime.h>
#include <cmath>

#define DIM 256
#define N_SEQ 3584
#define INNER 512
#define HEADS 8
#define DHEAD 64
#define LG 512       // downsampled K/V length
#define BATCH 2

// ---------------------------------------------------------------------------
// GEMM 1: Q = w_q (512x256) @ x[b] (256x3584)  -> q_buf (b,512,3584)
// 64x64 tile, BK=32, 4x4 acc/thread.
// NOTE (r5 analysis): 128x128/8x8 tiling rejected — grid would drop to
// 64-112 blocks (<50% CU occupancy), net slower than LDS-bound 64x64 at
// full occupancy for these shapes.
// ---------------------------------------------------------------------------
__global__ __launch_bounds__(256) void gemm_q(const float* __restrict__ W,
                                              const float* __restrict__ X,
                                              float* __restrict__ Q) {
  const int b  = blockIdx.z;
  const int n0 = blockIdx.x * 64;
  const int m0 = blockIdx.y * 64;
  const float* Xb = X + (size_t)b * DIM * N_SEQ;
  float* Qb = Q + (size_t)b * INNER * N_SEQ;
  __shared__ float As[32][68];
  __shared__ float Bs[32][64];
  const int tid = threadIdx.x;
  const int tn = tid & 15, tm = tid >> 4;
  float acc[4][4] = {};
  for (int k0 = 0; k0 < DIM; k0 += 32) {
    #pragma unroll
    for (int i = tid; i < 2048; i += 256) {
      int kk = i & 31, mm = i >> 5;
      As[kk][mm] = W[(m0 + mm) * DIM + k0 + kk];
    }
    #pragma unroll
    for (int i = tid; i < 2048; i += 256) {
      int nn = i & 63, kk2 = i >> 6;
      Bs[kk2][nn] = Xb[(size_t)(k0 + kk2) * N_SEQ + n0 + nn];
    }
    __syncthreads();
    #pragma unroll
    for (int kk = 0; kk < 32; ++kk) {
      float4 av = *(const float4*)&As[kk][tm * 4];
      float4 bv = *(const float4*)&Bs[kk][tn * 4];
      float aa[4] = {av.x, av.y, av.z, av.w};
      float bb[4] = {bv.x, bv.y, bv.z, bv.w};
      #pragma unroll
      for (int i = 0; i < 4; ++i)
        #pragma unroll
        for (int j = 0; j < 4; ++j)
          acc[i][j] += aa[i] * bb[j];
    }
    __syncthreads();
  }
  #pragma unroll
  for (int i = 0; i < 4; ++i)
    #pragma unroll
    for (int j = 0; j < 4; ++j)
      Qb[(size_t)(m0 + tm * 4 + i) * N_SEQ + n0 + tn * 4 + j] = acc[i][j];
}

// ---------------------------------------------------------------------------
// GEMM 2: KV = w_kv (1024 x 1792) @ xk[b] (1792 x 512)  (gather on x)
//   xk[m][ll] = x[b, m/7, ll*7 + m%7]
// ---------------------------------------------------------------------------
__global__ __launch_bounds__(256) void gemm_kv(const float* __restrict__ Wkv,
                                               const float* __restrict__ X,
                                               float* __restrict__ KV) {
  const int b  = blockIdx.z;
  const int l0 = blockIdx.x * 64;
  const int m0 = blockIdx.y * 64;
  const float* Xb = X + (size_t)b * DIM * N_SEQ;
  float* KVb = KV + (size_t)b * 2 * INNER * LG;
  __shared__ float As[32][68];
  __shared__ float Bs[32][64];
  const int tid = threadIdx.x;
  const int tn = tid & 15, tm = tid >> 4;
  float acc[4][4] = {};
  for (int k0 = 0; k0 < 1792; k0 += 32) {
    #pragma unroll
    for (int i = tid; i < 2048; i += 256) {
      int kk = i & 31, mm = i >> 5;
      As[kk][mm] = Wkv[(m0 + mm) * 1792 + k0 + kk];
    }
    #pragma unroll
    for (int i = tid; i < 2048; i += 256) {
      int nn = i & 63, kk2 = i >> 6;
      int m = k0 + kk2;
      int c = m / 7, j = m - c * 7;
      Bs[kk2][nn] = Xb[(size_t)c * N_SEQ + (l0 + nn) * 7 + j];
    }
    __syncthreads();
    #pragma unroll
    for (int kk = 0; kk < 32; ++kk) {
      float4 av = *(const float4*)&As[kk][tm * 4];
      float4 bv = *(const float4*)&Bs[kk][tn * 4];
      float aa[4] = {av.x, av.y, av.z, av.w};
      float bb[4] = {bv.x, bv.y, bv.z, bv.w};
      #pragma unroll
      for (int i = 0; i < 4; ++i)
        #pragma unroll
        for (int j = 0; j < 4; ++j)
          acc[i][j] += aa[i] * bb[j];
    }
    __syncthreads();
  }
  #pragma unroll
  for (int i = 0; i < 4; ++i)
    #pragma unroll
    for (int j = 0; j < 4; ++j)
      KVb[(size_t)(m0 + tm * 4 + i) * LG + l0 + tn * 4 + j] = acc[i][j];
}

// ---------------------------------------------------------------------------
// Attention v2: register-tiled 2 q-rows x 8 j-cols per thread.
// For each combo (a,e,h): Q rows 1792 x 64 attend K/V (512 x 64)
//   Q[r][d]  = q_buf[a][h*64+d][n(r)]  with n(r) = (r/7)*14 + e*7 + r%7
//   K[j][d]  = kv_buf[e][h*64+d][j]
//   V[j][d]  = kv_buf[e][512 + h*64+d][j]
//   O -> ao_buf[a][h*64+d][n(r)]
// Thread (rp=tid>>3, jg=tid&7): rows {2rp, 2rp+1}, cols j = jg + 8*i, i=0..7
// (strided j keeps K/V row reads conflict-free: 8 rows land 4 banks apart).
// Row reductions via shfl_xor over the 8 jg lanes (masks 1,2,4).
// ---------------------------------------------------------------------------
__global__ __launch_bounds__(256, 2) void attn(const float* __restrict__ Q,
                                               const float* __restrict__ KV,
                                               float* __restrict__ AO) {
  const int combo = blockIdx.y;
  const int a = combo >> 4, e = (combo >> 3) & 1, h = combo & 7;
  const int r0 = blockIdx.x * 64;
  const float* Qp = Q  + ((size_t)a * INNER + h * DHEAD) * N_SEQ;
  const float* Kp = KV + ((size_t)e * 2 * INNER + h * DHEAD) * LG;
  const float* Vp = KV + ((size_t)e * 2 * INNER + INNER + h * DHEAD) * LG;
  float* Op = AO + ((size_t)a * INNER + h * DHEAD) * N_SEQ;

  __shared__ float Qs[64][68];
  __shared__ float Ks[64][68];
  __shared__ float Vs[64][68];

  const int tid = threadIdx.x;
  const int rp  = tid >> 3;        // 0..31
  const int jg  = tid & 7;         // 0..7
  const int ra  = rp * 2, rb = ra + 1;

  // stage Q tile
  for (int i = tid; i < 4096; i += 256) {
    int dd = i >> 6, r2 = i & 63;
    int r = r0 + r2;
    int c = r / 7, p = r - c * 7;
    int n = c * 14 + e * 7 + p;
    Qs[r2][dd] = Qp[(size_t)dd * N_SEQ + n];
  }

  float oa[64], ob[64];
  #pragma unroll
  for (int d = 0; d < 64; ++d) { oa[d] = 0.f; ob[d] = 0.f; }
  float m_a = -INFINITY, l_a = 0.f;
  float m_b = -INFINITY, l_b = 0.f;
  const float scale = 0.125f;  // 64^-0.5

  for (int t = 0; t < 8; ++t) {
    const int j0 = t * 64;
    __syncthreads();
    for (int i = tid; i < 4096; i += 256) {
      int dd = i >> 6, jj = i & 63;
      Ks[jj][dd] = Kp[(size_t)dd * LG + j0 + jj];
      Vs[jj][dd] = Vp[(size_t)dd * LG + j0 + jj];
    }
    __syncthreads();

    // S-phase: 2 rows x 8 strided cols
    float sa[8], sb[8];
    #pragma unroll
    for (int i = 0; i < 8; ++i) { sa[i] = 0.f; sb[i] = 0.f; }
    #pragma unroll
    for (int d0 = 0; d0 < 64; d0 += 4) {
      float4 qa = *(const float4*)&Qs[ra][d0];
      float4 qb = *(const float4*)&Qs[rb][d0];
      #pragma unroll
      for (int i = 0; i < 8; ++i) {
        float4 kv4 = *(const float4*)&Ks[jg + 8 * i][d0];
        sa[i] += qa.x * kv4.x + qa.y * kv4.y + qa.z * kv4.z + qa.w * kv4.w;
        sb[i] += qb.x * kv4.x + qb.y * kv4.y + qb.z * kv4.z + qb.w * kv4.w;
      }
    }

    // online softmax (row reductions across the 8 jg lanes)
    float ta = -INFINITY, tb = -INFINITY;
    #pragma unroll
    for (int i = 0; i < 8; ++i) {
      sa[i] *= scale; sb[i] *= scale;
      ta = fmaxf(ta, sa[i]); tb = fmaxf(tb, sb[i]);
    }
    ta = fmaxf(ta, __shfl_xor(ta, 1)); tb = fmaxf(tb, __shfl_xor(tb, 1));
    ta = fmaxf(ta, __shfl_xor(ta, 2)); tb = fmaxf(tb, __shfl_xor(tb, 2));
    ta = fmaxf(ta, __shfl_xor(ta, 4)); tb = fmaxf(tb, __shfl_xor(tb, 4));
    float mna = fmaxf(m_a, ta), mnb = fmaxf(m_b, tb);
    float ca = __expf(m_a - mna), cb = __expf(m_b - mnb);
    float lsa = 0.f, lsb = 0.f;
    #pragma unroll
    for (int i = 0; i < 8; ++i) {
      sa[i] = __expf(sa[i] - mna); lsa += sa[i];
      sb[i] = __expf(sb[i] - mnb); lsb += sb[i];
    }
    lsa += __shfl_xor(lsa, 1); lsb += __shfl_xor(lsb, 1);
    lsa += __shfl_xor(lsa, 2); lsb += __shfl_xor(lsb, 2);
    lsa += __shfl_xor(lsa, 4); lsb += __shfl_xor(lsb, 4);
    l_a = l_a * ca + lsa;  m_a = mna;
    l_b = l_b * cb + lsb;  m_b = mnb;

    // rescale O only when some row max actually grew (wave-uniform test)
    if (!__all(ca == 1.0f && cb == 1.0f)) {
      #pragma unroll
      for (int d = 0; d < 64; ++d) { oa[d] *= ca; ob[d] *= cb; }
    }

    // PV: V row shared by both q-rows
    #pragma unroll
    for (int i = 0; i < 8; ++i) {
      const float pa = sa[i], pb = sb[i];
      const float* vrow = Vs[jg + 8 * i];
      #pragma unroll
      for (int d0 = 0; d0 < 64; d0 += 4) {
        float4 vv = *(const float4*)&vrow[d0];
        oa[d0 + 0] += pa * vv.x; oa[d0 + 1] += pa * vv.y;
        oa[d0 + 2] += pa * vv.z; oa[d0 + 3] += pa * vv.w;
        ob[d0 + 0] += pb * vv.x; ob[d0 + 1] += pb * vv.y;
        ob[d0 + 2] += pb * vv.z; ob[d0 + 3] += pb * vv.w;
      }
    }
  }

  // reduce partial O across the 8 jg lanes of each row-pair group
  #pragma unroll
  for (int d = 0; d < 64; ++d) {
    oa[d] += __shfl_xor(oa[d], 1); ob[d] += __shfl_xor(ob[d], 1);
    oa[d] += __shfl_xor(oa[d], 2); ob[d] += __shfl_xor(ob[d], 2);
    oa[d] += __shfl_xor(oa[d], 4); ob[d] += __shfl_xor(ob[d], 4);
  }
  const float rla = 1.0f / l_a, rlb = 1.0f / l_b;

  __syncthreads();
  if (jg == 0) {
    #pragma unroll
    for (int d = 0; d < 64; ++d) {
      Qs[ra][d] = oa[d] * rla;
      Qs[rb][d] = ob[d] * rlb;
    }
  }
  __syncthreads();
  for (int i = tid; i < 4096; i += 256) {
    int dd = i >> 6, r2 = i & 63;
    int r = r0 + r2;
    int c = r / 7, p = r - c * 7;
    int n = c * 14 + e * 7 + p;
    Op[(size_t)dd * N_SEQ + n] = Qs[r2][dd];
  }
}

// ---------------------------------------------------------------------------
// GEMM 3: out = w_out (256x512) @ ao[b] (512x3584) + b_out
// ---------------------------------------------------------------------------
__global__ __launch_bounds__(256) void gemm_out(const float* __restrict__ W,
                                                const float* __restrict__ AO,
                                                const float* __restrict__ bias,
                                                float* __restrict__ Out) {
  const int b  = blockIdx.z;
  const int n0 = blockIdx.x * 64;
  const int m0 = blockIdx.y * 64;
  const float* Ab = AO + (size_t)b * INNER * N_SEQ;
  float* Ob = Out + (size_t)b * DIM * N_SEQ;
  __shared__ float As[32][68];
  __shared__ float Bs[32][64];
  const int tid = threadIdx.x;
  const int tn = tid & 15, tm = tid >> 4;
  float acc[4][4] = {};
  for (int k0 = 0; k0 < INNER; k0 += 32) {
    #pragma unroll
    for (int i = tid; i < 2048; i += 256) {
      int kk = i & 31, mm = i >> 5;
      As[kk][mm] = W[(m0 + mm) * INNER + k0 + kk];
    }
    #pragma unroll
    for (int i = tid; i < 2048; i += 256) {
      int nn = i & 63, kk2 = i >> 6;
      Bs[kk2][nn] = Ab[(size_t)(k0 + kk2) * N_SEQ + n0 + nn];
    }
    __syncthreads();
    #pragma unroll
    for (int kk = 0; kk < 32; ++kk) {
      float4 av = *(const float4*)&As[kk][tm * 4];
      float4 bv = *(const float4*)&Bs[kk][tn * 4];
      float aa[4] = {av.x, av.y, av.z, av.w};
      float bb[4] = {bv.x, bv.y, bv.z, bv.w};
      #pragma unroll
      for (int i = 0; i < 4; ++i)
        #pragma unroll
        for (int j = 0; j < 4; ++j)
          acc[i][j] += aa[i] * bb[j];
    }
    __syncthreads();
  }
  #pragma unroll
  for (int i = 0; i < 4; ++i) {
    float bv_ = bias[m0 + tm * 4 + i];
    #pragma unroll
    for (int j = 0; j < 4; ++j)
      Ob[(size_t)(m0 + tm * 4 + i) * N_SEQ + n0 + tn * 4 + j] = acc[i][j] + bv_;
  }
}

// ---------------------------------------------------------------------------
extern "C" void kernel_launch(void* const* d_in, const int* in_sizes, int n_in,
                              void* d_out, int out_size, void* d_ws, size_t ws_size,
                              hipStream_t stream) {
  const float* x     = (const float*)d_in[0];
  const float* w_q   = (const float*)d_in[1];
  const float* w_kv  = (const float*)d_in[2];
  const float* w_out = (const float*)d_in[3];
  const float* b_out = (const float*)d_in[4];
  float* out = (float*)d_out;

  float* q_buf  = (float*)d_ws;                                  // 2*512*3584
  float* kv_buf = q_buf + (size_t)BATCH * INNER * N_SEQ;         // 2*1024*512
  float* ao_buf = kv_buf + (size_t)BATCH * 2 * INNER * LG;       // 2*512*3584

  gemm_q  <<<dim3(56, 8, 2),  256, 0, stream>>>(w_q, x, q_buf);
  gemm_kv <<<dim3(8, 16, 2),  256, 0, stream>>>(w_kv, x, kv_buf);
  attn    <<<dim3(28, 32),    256, 0, stream>>>(q_buf, kv_buf, ao_buf);
  gemm_out<<<dim3(56, 4, 2),  256, 0, stream>>>(w_out, ao_buf, b_out, out);
}

// Round 7
// 503.664 us; speedup vs baseline: 1.3228x; 1.3228x over previous
//
#include <hip/hip_runtime.h>
#include <cmath>

#define DIM 256
#define N_SEQ 3584
#define INNER 512
#define HEADS 8
#define DHEAD 64
#define LG 512       // downsampled K/V length
#define BATCH 2

// ---------------------------------------------------------------------------
// GEMM 1: Q = w_q (512x256) @ x[b] (256x3584)  -> q_buf (b,512,3584)
// 64x64 tile, BK=32, 4x4 acc/thread.
// ---------------------------------------------------------------------------
__global__ __launch_bounds__(256) void gemm_q(const float* __restrict__ W,
                                              const float* __restrict__ X,
                                              float* __restrict__ Q) {
  const int b  = blockIdx.z;
  const int n0 = blockIdx.x * 64;
  const int m0 = blockIdx.y * 64;
  const float* Xb = X + (size_t)b * DIM * N_SEQ;
  float* Qb = Q + (size_t)b * INNER * N_SEQ;
  __shared__ float As[32][68];
  __shared__ float Bs[32][64];
  const int tid = threadIdx.x;
  const int tn = tid & 15, tm = tid >> 4;
  float acc[4][4] = {};
  for (int k0 = 0; k0 < DIM; k0 += 32) {
    #pragma unroll
    for (int i = tid; i < 2048; i += 256) {
      int kk = i & 31, mm = i >> 5;
      As[kk][mm] = W[(m0 + mm) * DIM + k0 + kk];
    }
    #pragma unroll
    for (int i = tid; i < 2048; i += 256) {
      int nn = i & 63, kk2 = i >> 6;
      Bs[kk2][nn] = Xb[(size_t)(k0 + kk2) * N_SEQ + n0 + nn];
    }
    __syncthreads();
    #pragma unroll
    for (int kk = 0; kk < 32; ++kk) {
      float4 av = *(const float4*)&As[kk][tm * 4];
      float4 bv = *(const float4*)&Bs[kk][tn * 4];
      float aa[4] = {av.x, av.y, av.z, av.w};
      float bb[4] = {bv.x, bv.y, bv.z, bv.w};
      #pragma unroll
      for (int i = 0; i < 4; ++i)
        #pragma unroll
        for (int j = 0; j < 4; ++j)
          acc[i][j] += aa[i] * bb[j];
    }
    __syncthreads();
  }
  #pragma unroll
  for (int i = 0; i < 4; ++i)
    #pragma unroll
    for (int j = 0; j < 4; ++j)
      Qb[(size_t)(m0 + tm * 4 + i) * N_SEQ + n0 + tn * 4 + j] = acc[i][j];
}

// ---------------------------------------------------------------------------
// GEMM 2 v2: KV = w_kv (1024 x 1792) @ xk[b] (1792 x 512), split-K x4.
// r5 counters: v1 was 285us @ 12% occupancy (256 blocks = 1 block/CU),
// latency-bound on stride-7 B-gather. v2: split k=1792 into 4 chunks of
// 448 (64 channels) -> 1024 blocks (4/CU, 16 waves); stage B by loading
// the CONTIGUOUS 448-float x-range per channel and transposing on store;
// pads: As stride 80 (bank step 16 = 2-way free, float4-aligned),
// Bs stride 68.
//   partial(kc=0) -> kv_buf, partial(kc=1..3) -> ao_buf (reduced before attn)
// ---------------------------------------------------------------------------
__global__ __launch_bounds__(256) void gemm_kv(const float* __restrict__ Wkv,
                                               const float* __restrict__ X,
                                               float* __restrict__ KVp,
                                               float* __restrict__ Pbuf) {
  const int bz = blockIdx.z;
  const int b  = bz >> 2;          // batch
  const int kc = bz & 3;           // k-chunk
  const int l0 = blockIdx.x * 64;
  const int m0 = blockIdx.y * 64;
  const int c0 = kc * 64;          // first channel of this chunk
  const float* Xb = X + (size_t)b * DIM * N_SEQ;

  __shared__ float As[56][80];   // [kk][mm], stride 80: 2-way write, aligned
  __shared__ float Bs[56][68];   // [kk][nn]

  const int tid = threadIdx.x;
  const int tn = tid & 15, tm = tid >> 4;
  float acc[4][4] = {};

  for (int s = 0; s < 8; ++s) {            // 8 sub-chunks of 8 channels (56 k)
    const int kbase = c0 * 7 + s * 56;     // global k offset
    const int cbase = c0 + s * 8;          // global channel offset
    // stage A: 56 x 64, global-contiguous runs of 56 floats per m-row
    #pragma unroll
    for (int i = tid; i < 3584; i += 256) {
      int kk = i % 56, mm = i / 56;
      As[kk][mm] = Wkv[(size_t)(m0 + mm) * 1792 + kbase + kk];
    }
    // stage B: 8 channels x 448 contiguous floats, transpose on store
    #pragma unroll
    for (int i = tid; i < 3584; i += 256) {
      int ch = i / 448, t = i % 448;
      float v = Xb[(size_t)(cbase + ch) * N_SEQ + l0 * 7 + t];
      Bs[ch * 7 + t % 7][t / 7] = v;
    }
    __syncthreads();
    #pragma unroll 8
    for (int kk = 0; kk < 56; ++kk) {
      float4 av = *(const float4*)&As[kk][tm * 4];
      float4 bv = *(const float4*)&Bs[kk][tn * 4];
      float aa[4] = {av.x, av.y, av.z, av.w};
      float bb[4] = {bv.x, bv.y, bv.z, bv.w};
      #pragma unroll
      for (int i = 0; i < 4; ++i)
        #pragma unroll
        for (int j = 0; j < 4; ++j)
          acc[i][j] += aa[i] * bb[j];
    }
    __syncthreads();
  }

  // partial store: kc==0 -> kv_buf, else Pbuf slab (kc-1)
  float* dst = (kc == 0) ? KVp : (Pbuf + (size_t)(kc - 1) * (BATCH * 2 * INNER * LG));
  dst += (size_t)b * 2 * INNER * LG;
  #pragma unroll
  for (int i = 0; i < 4; ++i)
    #pragma unroll
    for (int j = 0; j < 4; ++j)
      dst[(size_t)(m0 + tm * 4 + i) * LG + l0 + tn * 4 + j] = acc[i][j];
}

// reduce: kv += p1 + p2 + p3   (1,048,576 floats = 262,144 float4)
__global__ __launch_bounds__(256) void kv_reduce(float* __restrict__ KVp,
                                                 const float* __restrict__ Pbuf) {
  const size_t i = ((size_t)blockIdx.x * 256 + threadIdx.x) * 4;
  const size_t n1 = (size_t)BATCH * 2 * INNER * LG;
  float4 a  = *(const float4*)&KVp[i];
  float4 p1 = *(const float4*)&Pbuf[i];
  float4 p2 = *(const float4*)&Pbuf[n1 + i];
  float4 p3 = *(const float4*)&Pbuf[2 * n1 + i];
  a.x += p1.x + p2.x + p3.x;
  a.y += p1.y + p2.y + p3.y;
  a.z += p1.z + p2.z + p3.z;
  a.w += p1.w + p2.w + p3.w;
  *(float4*)&KVp[i] = a;
}

// ---------------------------------------------------------------------------
// Attention v2: register-tiled 2 q-rows x 8 j-cols per thread.
// For each combo (a,e,h): Q rows 1792 x 64 attend K/V (512 x 64)
//   Q[r][d]  = q_buf[a][h*64+d][n(r)]  with n(r) = (r/7)*14 + e*7 + r%7
// Thread (rp=tid>>3, jg=tid&7): rows {2rp, 2rp+1}, cols j = jg + 8*i
// ---------------------------------------------------------------------------
__global__ __launch_bounds__(256, 2) void attn(const float* __restrict__ Q,
                                               const float* __restrict__ KV,
                                               float* __restrict__ AO) {
  const int combo = blockIdx.y;
  const int a = combo >> 4, e = (combo >> 3) & 1, h = combo & 7;
  const int r0 = blockIdx.x * 64;
  const float* Qp = Q  + ((size_t)a * INNER + h * DHEAD) * N_SEQ;
  const float* Kp = KV + ((size_t)e * 2 * INNER + h * DHEAD) * LG;
  const float* Vp = KV + ((size_t)e * 2 * INNER + INNER + h * DHEAD) * LG;
  float* Op = AO + ((size_t)a * INNER + h * DHEAD) * N_SEQ;

  __shared__ float Qs[64][68];
  __shared__ float Ks[64][68];
  __shared__ float Vs[64][68];

  const int tid = threadIdx.x;
  const int rp  = tid >> 3;        // 0..31
  const int jg  = tid & 7;         // 0..7
  const int ra  = rp * 2, rb = ra + 1;

  for (int i = tid; i < 4096; i += 256) {
    int dd = i >> 6, r2 = i & 63;
    int r = r0 + r2;
    int c = r / 7, p = r - c * 7;
    int n = c * 14 + e * 7 + p;
    Qs[r2][dd] = Qp[(size_t)dd * N_SEQ + n];
  }

  float oa[64], ob[64];
  #pragma unroll
  for (int d = 0; d < 64; ++d) { oa[d] = 0.f; ob[d] = 0.f; }
  float m_a = -INFINITY, l_a = 0.f;
  float m_b = -INFINITY, l_b = 0.f;
  const float scale = 0.125f;  // 64^-0.5

  for (int t = 0; t < 8; ++t) {
    const int j0 = t * 64;
    __syncthreads();
    for (int i = tid; i < 4096; i += 256) {
      int dd = i >> 6, jj = i & 63;
      Ks[jj][dd] = Kp[(size_t)dd * LG + j0 + jj];
      Vs[jj][dd] = Vp[(size_t)dd * LG + j0 + jj];
    }
    __syncthreads();

    float sa[8], sb[8];
    #pragma unroll
    for (int i = 0; i < 8; ++i) { sa[i] = 0.f; sb[i] = 0.f; }
    #pragma unroll
    for (int d0 = 0; d0 < 64; d0 += 4) {
      float4 qa = *(const float4*)&Qs[ra][d0];
      float4 qb = *(const float4*)&Qs[rb][d0];
      #pragma unroll
      for (int i = 0; i < 8; ++i) {
        float4 kv4 = *(const float4*)&Ks[jg + 8 * i][d0];
        sa[i] += qa.x * kv4.x + qa.y * kv4.y + qa.z * kv4.z + qa.w * kv4.w;
        sb[i] += qb.x * kv4.x + qb.y * kv4.y + qb.z * kv4.z + qb.w * kv4.w;
      }
    }

    float ta = -INFINITY, tb = -INFINITY;
    #pragma unroll
    for (int i = 0; i < 8; ++i) {
      sa[i] *= scale; sb[i] *= scale;
      ta = fmaxf(ta, sa[i]); tb = fmaxf(tb, sb[i]);
    }
    ta = fmaxf(ta, __shfl_xor(ta, 1)); tb = fmaxf(tb, __shfl_xor(tb, 1));
    ta = fmaxf(ta, __shfl_xor(ta, 2)); tb = fmaxf(tb, __shfl_xor(tb, 2));
    ta = fmaxf(ta, __shfl_xor(ta, 4)); tb = fmaxf(tb, __shfl_xor(tb, 4));
    float mna = fmaxf(m_a, ta), mnb = fmaxf(m_b, tb);
    float ca = __expf(m_a - mna), cb = __expf(m_b - mnb);
    float lsa = 0.f, lsb = 0.f;
    #pragma unroll
    for (int i = 0; i < 8; ++i) {
      sa[i] = __expf(sa[i] - mna); lsa += sa[i];
      sb[i] = __expf(sb[i] - mnb); lsb += sb[i];
    }
    lsa += __shfl_xor(lsa, 1); lsb += __shfl_xor(lsb, 1);
    lsa += __shfl_xor(lsa, 2); lsb += __shfl_xor(lsb, 2);
    lsa += __shfl_xor(lsa, 4); lsb += __shfl_xor(lsb, 4);
    l_a = l_a * ca + lsa;  m_a = mna;
    l_b = l_b * cb + lsb;  m_b = mnb;

    if (!__all(ca == 1.0f && cb == 1.0f)) {
      #pragma unroll
      for (int d = 0; d < 64; ++d) { oa[d] *= ca; ob[d] *= cb; }
    }

    #pragma unroll
    for (int i = 0; i < 8; ++i) {
      const float pa = sa[i], pb = sb[i];
      const float* vrow = Vs[jg + 8 * i];
      #pragma unroll
      for (int d0 = 0; d0 < 64; d0 += 4) {
        float4 vv = *(const float4*)&vrow[d0];
        oa[d0 + 0] += pa * vv.x; oa[d0 + 1] += pa * vv.y;
        oa[d0 + 2] += pa * vv.z; oa[d0 + 3] += pa * vv.w;
        ob[d0 + 0] += pb * vv.x; ob[d0 + 1] += pb * vv.y;
        ob[d0 + 2] += pb * vv.z; ob[d0 + 3] += pb * vv.w;
      }
    }
  }

  #pragma unroll
  for (int d = 0; d < 64; ++d) {
    oa[d] += __shfl_xor(oa[d], 1); ob[d] += __shfl_xor(ob[d], 1);
    oa[d] += __shfl_xor(oa[d], 2); ob[d] += __shfl_xor(ob[d], 2);
    oa[d] += __shfl_xor(oa[d], 4); ob[d] += __shfl_xor(ob[d], 4);
  }
  const float rla = 1.0f / l_a, rlb = 1.0f / l_b;

  __syncthreads();
  if (jg == 0) {
    #pragma unroll
    for (int d = 0; d < 64; ++d) {
      Qs[ra][d] = oa[d] * rla;
      Qs[rb][d] = ob[d] * rlb;
    }
  }
  __syncthreads();
  for (int i = tid; i < 4096; i += 256) {
    int dd = i >> 6, r2 = i & 63;
    int r = r0 + r2;
    int c = r / 7, p = r - c * 7;
    int n = c * 14 + e * 7 + p;
    Op[(size_t)dd * N_SEQ + n] = Qs[r2][dd];
  }
}

// ---------------------------------------------------------------------------
// GEMM 3: out = w_out (256x512) @ ao[b] (512x3584) + b_out
// ---------------------------------------------------------------------------
__global__ __launch_bounds__(256) void gemm_out(const float* __restrict__ W,
                                                const float* __restrict__ AO,
                                                const float* __restrict__ bias,
                                                float* __restrict__ Out) {
  const int b  = blockIdx.z;
  const int n0 = blockIdx.x * 64;
  const int m0 = blockIdx.y * 64;
  const float* Ab = AO + (size_t)b * INNER * N_SEQ;
  float* Ob = Out + (size_t)b * DIM * N_SEQ;
  __shared__ float As[32][68];
  __shared__ float Bs[32][64];
  const int tid = threadIdx.x;
  const int tn = tid & 15, tm = tid >> 4;
  float acc[4][4] = {};
  for (int k0 = 0; k0 < INNER; k0 += 32) {
    #pragma unroll
    for (int i = tid; i < 2048; i += 256) {
      int kk = i & 31, mm = i >> 5;
      As[kk][mm] = W[(m0 + mm) * INNER + k0 + kk];
    }
    #pragma unroll
    for (int i = tid; i < 2048; i += 256) {
      int nn = i & 63, kk2 = i >> 6;
      Bs[kk2][nn] = Ab[(size_t)(k0 + kk2) * N_SEQ + n0 + nn];
    }
    __syncthreads();
    #pragma unroll
    for (int kk = 0; kk < 32; ++kk) {
      float4 av = *(const float4*)&As[kk][tm * 4];
      float4 bv = *(const float4*)&Bs[kk][tn * 4];
      float aa[4] = {av.x, av.y, av.z, av.w};
      float bb[4] = {bv.x, bv.y, bv.z, bv.w};
      #pragma unroll
      for (int i = 0; i < 4; ++i)
        #pragma unroll
        for (int j = 0; j < 4; ++j)
          acc[i][j] += aa[i] * bb[j];
    }
    __syncthreads();
  }
  #pragma unroll
  for (int i = 0; i < 4; ++i) {
    float bv_ = bias[m0 + tm * 4 + i];
    #pragma unroll
    for (int j = 0; j < 4; ++j)
      Ob[(size_t)(m0 + tm * 4 + i) * N_SEQ + n0 + tn * 4 + j] = acc[i][j] + bv_;
  }
}

// ---------------------------------------------------------------------------
extern "C" void kernel_launch(void* const* d_in, const int* in_sizes, int n_in,
                              void* d_out, int out_size, void* d_ws, size_t ws_size,
                              hipStream_t stream) {
  const float* x     = (const float*)d_in[0];
  const float* w_q   = (const float*)d_in[1];
  const float* w_kv  = (const float*)d_in[2];
  const float* w_out = (const float*)d_in[3];
  const float* b_out = (const float*)d_in[4];
  float* out = (float*)d_out;

  float* q_buf  = (float*)d_ws;                                  // 2*512*3584
  float* kv_buf = q_buf + (size_t)BATCH * INNER * N_SEQ;         // 2*1024*512
  float* ao_buf = kv_buf + (size_t)BATCH * 2 * INNER * LG;       // 2*512*3584
  // ao_buf doubles as split-K partial storage (3 x 1,048,576 floats) for
  // gemm_kv; consumed by kv_reduce before attn writes ao_buf.

  gemm_q   <<<dim3(56, 8, 2),  256, 0, stream>>>(w_q, x, q_buf);
  gemm_kv  <<<dim3(8, 16, 8),  256, 0, stream>>>(w_kv, x, kv_buf, ao_buf);
  kv_reduce<<<dim3(1024),      256, 0, stream>>>(kv_buf, ao_buf);
  attn     <<<dim3(28, 32),    256, 0, stream>>>(q_buf, kv_buf, ao_buf);
  gemm_out <<<dim3(56, 4, 2),  256, 0, stream>>>(w_out, ao_buf, b_out, out);
}

// Round 8
// 482.942 us; speedup vs baseline: 1.3796x; 1.0429x over previous
//
#include <hip/hip_runtime.h>
#include <cmath>

#define DIM 256
#define N_SEQ 3584
#define INNER 512
#define HEADS 8
#define DHEAD 64
#define LG 512       // downsampled K/V length
#define BATCH 2

typedef __attribute__((ext_vector_type(8))) short bf16x8;   // 8 bf16 = 4 VGPR
typedef __attribute__((ext_vector_type(4))) float f32x4;

// RNE fp32 -> bf16 (bit pattern)
static __device__ __forceinline__ unsigned short f2b(float v) {
  unsigned u = __float_as_uint(v);
  u = u + 0x7fffu + ((u >> 16) & 1u);
  return (unsigned short)(u >> 16);
}
static __device__ __forceinline__ float b2f(unsigned short h) {
  return __uint_as_float((unsigned)h << 16);
}

#define MFMA(d, a, b) d = __builtin_amdgcn_mfma_f32_16x16x32_bf16(a, b, d, 0, 0, 0)

// ---------------------------------------------------------------------------
// GEMM 1 (split-bf16 MFMA): Q = w_q (512x256) @ x[b] (256x3584)
// 128x128 block, BK=32, 4 waves 2x2 (64x64/wave, 4x4 16x16 frags).
// LDS planes [row][40] bf16: stride 80B -> 2-way bank (free), 16B-aligned.
// A=[M][K], B stored transposed [N][K] (m92 B^T fragment pattern).
// ---------------------------------------------------------------------------
__global__ __launch_bounds__(256) void gemm_q(const float* __restrict__ W,
                                              const float* __restrict__ X,
                                              float* __restrict__ Q) {
  const int b  = blockIdx.z;
  const int n0 = blockIdx.x * 128;
  const int m0 = blockIdx.y * 128;
  const float* Xb = X + (size_t)b * DIM * N_SEQ;
  float* Qb = Q + (size_t)b * INNER * N_SEQ;
  __shared__ unsigned short Ah[128 * 40], Al[128 * 40];
  __shared__ unsigned short Bh[128 * 40], Bl[128 * 40];
  const int tid = threadIdx.x;
  const int lane = tid & 63, wid = tid >> 6;
  const int wr = wid >> 1, wc = wid & 1;
  const int lr = lane & 15, lk = (lane >> 4) * 8;

  f32x4 acc[4][4] = {};

  for (int k0 = 0; k0 < DIM; k0 += 32) {
    for (int i = tid; i < 4096; i += 256) {          // A tile 128x32
      int kk = i & 31, mm = i >> 5;
      float v = W[(size_t)(m0 + mm) * DIM + k0 + kk];
      unsigned short h = f2b(v);
      Ah[mm * 40 + kk] = h; Al[mm * 40 + kk] = f2b(v - b2f(h));
    }
    for (int i = tid; i < 4096; i += 256) {          // B tile 32x128 -> Bt[n][k]
      int nn = i & 127, kk = i >> 7;
      float v = Xb[(size_t)(k0 + kk) * N_SEQ + n0 + nn];
      unsigned short h = f2b(v);
      Bh[nn * 40 + kk] = h; Bl[nn * 40 + kk] = f2b(v - b2f(h));
    }
    __syncthreads();
    bf16x8 ah[4], al[4], bh[4], bl[4];
    #pragma unroll
    for (int f = 0; f < 4; ++f) {
      int ar = (wr * 64 + f * 16 + lr) * 40 + lk;
      ah[f] = *(const bf16x8*)&Ah[ar]; al[f] = *(const bf16x8*)&Al[ar];
      int br = (wc * 64 + f * 16 + lr) * 40 + lk;
      bh[f] = *(const bf16x8*)&Bh[br]; bl[f] = *(const bf16x8*)&Bl[br];
    }
    #pragma unroll
    for (int fi = 0; fi < 4; ++fi)
      #pragma unroll
      for (int fj = 0; fj < 4; ++fj) {
        MFMA(acc[fi][fj], ah[fi], bh[fj]);
        MFMA(acc[fi][fj], ah[fi], bl[fj]);
        MFMA(acc[fi][fj], al[fi], bh[fj]);
      }
    __syncthreads();
  }
  const int crow = (lane >> 4) * 4, ccol = lane & 15;
  #pragma unroll
  for (int fi = 0; fi < 4; ++fi)
    #pragma unroll
    for (int fj = 0; fj < 4; ++fj) {
      int row = m0 + wr * 64 + fi * 16 + crow;
      int col = n0 + wc * 64 + fj * 16 + ccol;
      #pragma unroll
      for (int r = 0; r < 4; ++r)
        Qb[(size_t)(row + r) * N_SEQ + col] = acc[fi][fj][r];
    }
}

// ---------------------------------------------------------------------------
// GEMM 2 (split-bf16 MFMA, split-K x4): KV = w_kv (1024x1792) @ xk (1792x512)
// Block 128(m) x 64(l); per kc: K=448 staged as 8 x 56 (8 contiguous-x
// channels), k in [56,64) zero-padded once -> 2 MFMA K-steps per stage.
// LDS planes [row][72] (stride 144B: 2-way free, 16B-aligned). 55.3KB.
// ---------------------------------------------------------------------------
__global__ __launch_bounds__(256) void gemm_kv(const float* __restrict__ Wkv,
                                               const float* __restrict__ X,
                                               float* __restrict__ KVp,
                                               float* __restrict__ Pbuf) {
  const int bz = blockIdx.z;
  const int b = bz >> 2, kc = bz & 3;
  const int l0 = blockIdx.x * 64;
  const int m0 = blockIdx.y * 128;
  const int c0 = kc * 64;
  const float* Xb = X + (size_t)b * DIM * N_SEQ;
  __shared__ unsigned short Ah[128 * 72], Al[128 * 72];
  __shared__ unsigned short Bh[64 * 72],  Bl[64 * 72];
  const int tid = threadIdx.x;
  const int lane = tid & 63, wid = tid >> 6;
  const int wr = wid >> 1, wc = wid & 1;           // wave tile 64x32
  const int lr = lane & 15, lk = (lane >> 4) * 8;

  // one-time zero fill of k-pad [56,64) (never overwritten by staging)
  for (int i = tid; i < 1024; i += 256) {
    int rr = i >> 3, kk = 56 + (i & 7);
    Ah[rr * 72 + kk] = 0; Al[rr * 72 + kk] = 0;
    if (rr < 64) { Bh[rr * 72 + kk] = 0; Bl[rr * 72 + kk] = 0; }
  }

  f32x4 acc[4][2] = {};

  for (int s = 0; s < 8; ++s) {
    const int kbase = c0 * 7 + s * 56;
    const int cbase = c0 + s * 8;
    for (int i = tid; i < 7168; i += 256) {          // A: 128 x 56
      int kk = i % 56, mm = i / 56;
      float v = Wkv[(size_t)(m0 + mm) * 1792 + kbase + kk];
      unsigned short h = f2b(v);
      Ah[mm * 72 + kk] = h; Al[mm * 72 + kk] = f2b(v - b2f(h));
    }
    for (int i = tid; i < 3584; i += 256) {          // B: 8 ch x 448 contiguous
      int ch = i / 448, t = i % 448;
      int l = t / 7, j = t - (t / 7) * 7;
      float v = Xb[(size_t)(cbase + ch) * N_SEQ + l0 * 7 + t];
      unsigned short h = f2b(v);
      int idx = l * 72 + ch * 7 + j;
      Bh[idx] = h; Bl[idx] = f2b(v - b2f(h));
    }
    __syncthreads();
    #pragma unroll
    for (int kh = 0; kh < 2; ++kh) {
      const int ko = kh * 32 + lk;
      bf16x8 ah[4], al[4], bh[2], bl[2];
      #pragma unroll
      for (int f = 0; f < 4; ++f) {
        int ar = (wr * 64 + f * 16 + lr) * 72 + ko;
        ah[f] = *(const bf16x8*)&Ah[ar]; al[f] = *(const bf16x8*)&Al[ar];
      }
      #pragma unroll
      for (int f = 0; f < 2; ++f) {
        int br = (wc * 32 + f * 16 + lr) * 72 + ko;
        bh[f] = *(const bf16x8*)&Bh[br]; bl[f] = *(const bf16x8*)&Bl[br];
      }
      #pragma unroll
      for (int fi = 0; fi < 4; ++fi)
        #pragma unroll
        for (int fj = 0; fj < 2; ++fj) {
          MFMA(acc[fi][fj], ah[fi], bh[fj]);
          MFMA(acc[fi][fj], ah[fi], bl[fj]);
          MFMA(acc[fi][fj], al[fi], bh[fj]);
        }
    }
    __syncthreads();
  }

  float* dst = (kc == 0) ? KVp : (Pbuf + (size_t)(kc - 1) * (BATCH * 2 * INNER * LG));
  dst += (size_t)b * 2 * INNER * LG;
  const int crow = (lane >> 4) * 4, ccol = lane & 15;
  #pragma unroll
  for (int fi = 0; fi < 4; ++fi)
    #pragma unroll
    for (int fj = 0; fj < 2; ++fj) {
      int row = m0 + wr * 64 + fi * 16 + crow;
      int col = l0 + wc * 32 + fj * 16 + ccol;
      #pragma unroll
      for (int r = 0; r < 4; ++r)
        dst[(size_t)(row + r) * LG + col] = acc[fi][fj][r];
    }
}

// reduce: kv += p1 + p2 + p3
__global__ __launch_bounds__(256) void kv_reduce(float* __restrict__ KVp,
                                                 const float* __restrict__ Pbuf) {
  const size_t i = ((size_t)blockIdx.x * 256 + threadIdx.x) * 4;
  const size_t n1 = (size_t)BATCH * 2 * INNER * LG;
  float4 a  = *(const float4*)&KVp[i];
  float4 p1 = *(const float4*)&Pbuf[i];
  float4 p2 = *(const float4*)&Pbuf[n1 + i];
  float4 p3 = *(const float4*)&Pbuf[2 * n1 + i];
  a.x += p1.x + p2.x + p3.x;
  a.y += p1.y + p2.y + p3.y;
  a.z += p1.z + p2.z + p3.z;
  a.w += p1.w + p2.w + p3.w;
  *(float4*)&KVp[i] = a;
}

// ---------------------------------------------------------------------------
// Attention (UNCHANGED from r7 passing version): register-tiled 2x8/thread.
// ---------------------------------------------------------------------------
__global__ __launch_bounds__(256, 2) void attn(const float* __restrict__ Q,
                                               const float* __restrict__ KV,
                                               float* __restrict__ AO) {
  const int combo = blockIdx.y;
  const int a = combo >> 4, e = (combo >> 3) & 1, h = combo & 7;
  const int r0 = blockIdx.x * 64;
  const float* Qp = Q  + ((size_t)a * INNER + h * DHEAD) * N_SEQ;
  const float* Kp = KV + ((size_t)e * 2 * INNER + h * DHEAD) * LG;
  const float* Vp = KV + ((size_t)e * 2 * INNER + INNER + h * DHEAD) * LG;
  float* Op = AO + ((size_t)a * INNER + h * DHEAD) * N_SEQ;

  __shared__ float Qs[64][68];
  __shared__ float Ks[64][68];
  __shared__ float Vs[64][68];

  const int tid = threadIdx.x;
  const int rp  = tid >> 3;
  const int jg  = tid & 7;
  const int ra  = rp * 2, rb = ra + 1;

  for (int i = tid; i < 4096; i += 256) {
    int dd = i >> 6, r2 = i & 63;
    int r = r0 + r2;
    int c = r / 7, p = r - c * 7;
    int n = c * 14 + e * 7 + p;
    Qs[r2][dd] = Qp[(size_t)dd * N_SEQ + n];
  }

  float oa[64], ob[64];
  #pragma unroll
  for (int d = 0; d < 64; ++d) { oa[d] = 0.f; ob[d] = 0.f; }
  float m_a = -INFINITY, l_a = 0.f;
  float m_b = -INFINITY, l_b = 0.f;
  const float scale = 0.125f;

  for (int t = 0; t < 8; ++t) {
    const int j0 = t * 64;
    __syncthreads();
    for (int i = tid; i < 4096; i += 256) {
      int dd = i >> 6, jj = i & 63;
      Ks[jj][dd] = Kp[(size_t)dd * LG + j0 + jj];
      Vs[jj][dd] = Vp[(size_t)dd * LG + j0 + jj];
    }
    __syncthreads();

    float sa[8], sb[8];
    #pragma unroll
    for (int i = 0; i < 8; ++i) { sa[i] = 0.f; sb[i] = 0.f; }
    #pragma unroll
    for (int d0 = 0; d0 < 64; d0 += 4) {
      float4 qa = *(const float4*)&Qs[ra][d0];
      float4 qb = *(const float4*)&Qs[rb][d0];
      #pragma unroll
      for (int i = 0; i < 8; ++i) {
        float4 kv4 = *(const float4*)&Ks[jg + 8 * i][d0];
        sa[i] += qa.x * kv4.x + qa.y * kv4.y + qa.z * kv4.z + qa.w * kv4.w;
        sb[i] += qb.x * kv4.x + qb.y * kv4.y + qb.z * kv4.z + qb.w * kv4.w;
      }
    }

    float ta = -INFINITY, tb = -INFINITY;
    #pragma unroll
    for (int i = 0; i < 8; ++i) {
      sa[i] *= scale; sb[i] *= scale;
      ta = fmaxf(ta, sa[i]); tb = fmaxf(tb, sb[i]);
    }
    ta = fmaxf(ta, __shfl_xor(ta, 1)); tb = fmaxf(tb, __shfl_xor(tb, 1));
    ta = fmaxf(ta, __shfl_xor(ta, 2)); tb = fmaxf(tb, __shfl_xor(tb, 2));
    ta = fmaxf(ta, __shfl_xor(ta, 4)); tb = fmaxf(tb, __shfl_xor(tb, 4));
    float mna = fmaxf(m_a, ta), mnb = fmaxf(m_b, tb);
    float ca = __expf(m_a - mna), cb = __expf(m_b - mnb);
    float lsa = 0.f, lsb = 0.f;
    #pragma unroll
    for (int i = 0; i < 8; ++i) {
      sa[i] = __expf(sa[i] - mna); lsa += sa[i];
      sb[i] = __expf(sb[i] - mnb); lsb += sb[i];
    }
    lsa += __shfl_xor(lsa, 1); lsb += __shfl_xor(lsb, 1);
    lsa += __shfl_xor(lsa, 2); lsb += __shfl_xor(lsb, 2);
    lsa += __shfl_xor(lsa, 4); lsb += __shfl_xor(lsb, 4);
    l_a = l_a * ca + lsa;  m_a = mna;
    l_b = l_b * cb + lsb;  m_b = mnb;

    if (!__all(ca == 1.0f && cb == 1.0f)) {
      #pragma unroll
      for (int d = 0; d < 64; ++d) { oa[d] *= ca; ob[d] *= cb; }
    }

    #pragma unroll
    for (int i = 0; i < 8; ++i) {
      const float pa = sa[i], pb = sb[i];
      const float* vrow = Vs[jg + 8 * i];
      #pragma unroll
      for (int d0 = 0; d0 < 64; d0 += 4) {
        float4 vv = *(const float4*)&vrow[d0];
        oa[d0 + 0] += pa * vv.x; oa[d0 + 1] += pa * vv.y;
        oa[d0 + 2] += pa * vv.z; oa[d0 + 3] += pa * vv.w;
        ob[d0 + 0] += pb * vv.x; ob[d0 + 1] += pb * vv.y;
        ob[d0 + 2] += pb * vv.z; ob[d0 + 3] += pb * vv.w;
      }
    }
  }

  #pragma unroll
  for (int d = 0; d < 64; ++d) {
    oa[d] += __shfl_xor(oa[d], 1); ob[d] += __shfl_xor(ob[d], 1);
    oa[d] += __shfl_xor(oa[d], 2); ob[d] += __shfl_xor(ob[d], 2);
    oa[d] += __shfl_xor(oa[d], 4); ob[d] += __shfl_xor(ob[d], 4);
  }
  const float rla = 1.0f / l_a, rlb = 1.0f / l_b;

  __syncthreads();
  if (jg == 0) {
    #pragma unroll
    for (int d = 0; d < 64; ++d) {
      Qs[ra][d] = oa[d] * rla;
      Qs[rb][d] = ob[d] * rlb;
    }
  }
  __syncthreads();
  for (int i = tid; i < 4096; i += 256) {
    int dd = i >> 6, r2 = i & 63;
    int r = r0 + r2;
    int c = r / 7, p = r - c * 7;
    int n = c * 14 + e * 7 + p;
    Op[(size_t)dd * N_SEQ + n] = Qs[r2][dd];
  }
}

// ---------------------------------------------------------------------------
// GEMM 3 (split-bf16 MFMA): out = w_out (256x512) @ ao[b] (512x3584) + b_out
// Block 64(m) x 128(n), BK=32, 4 waves (32x64/wave, 2x4 frags). LDS 30KB.
// ---------------------------------------------------------------------------
__global__ __launch_bounds__(256) void gemm_out(const float* __restrict__ W,
                                                const float* __restrict__ AO,
                                                const float* __restrict__ bias,
                                                float* __restrict__ Out) {
  const int b  = blockIdx.z;
  const int n0 = blockIdx.x * 128;
  const int m0 = blockIdx.y * 64;
  const float* Ab = AO + (size_t)b * INNER * N_SEQ;
  float* Ob = Out + (size_t)b * DIM * N_SEQ;
  __shared__ unsigned short Ah[64 * 40], Al[64 * 40];
  __shared__ unsigned short Bh[128 * 40], Bl[128 * 40];
  const int tid = threadIdx.x;
  const int lane = tid & 63, wid = tid >> 6;
  const int wr = wid >> 1, wc = wid & 1;           // wave tile 32x64
  const int lr = lane & 15, lk = (lane >> 4) * 8;

  f32x4 acc[2][4] = {};

  for (int k0 = 0; k0 < INNER; k0 += 32) {
    for (int i = tid; i < 2048; i += 256) {          // A tile 64x32
      int kk = i & 31, mm = i >> 5;
      float v = W[(size_t)(m0 + mm) * INNER + k0 + kk];
      unsigned short h = f2b(v);
      Ah[mm * 40 + kk] = h; Al[mm * 40 + kk] = f2b(v - b2f(h));
    }
    for (int i = tid; i < 4096; i += 256) {          // B tile 32x128 -> Bt[n][k]
      int nn = i & 127, kk = i >> 7;
      float v = Ab[(size_t)(k0 + kk) * N_SEQ + n0 + nn];
      unsigned short h = f2b(v);
      Bh[nn * 40 + kk] = h; Bl[nn * 40 + kk] = f2b(v - b2f(h));
    }
    __syncthreads();
    bf16x8 ah[2], al[2], bh[4], bl[4];
    #pragma unroll
    for (int f = 0; f < 2; ++f) {
      int ar = (wr * 32 + f * 16 + lr) * 40 + lk;
      ah[f] = *(const bf16x8*)&Ah[ar]; al[f] = *(const bf16x8*)&Al[ar];
    }
    #pragma unroll
    for (int f = 0; f < 4; ++f) {
      int br = (wc * 64 + f * 16 + lr) * 40 + lk;
      bh[f] = *(const bf16x8*)&Bh[br]; bl[f] = *(const bf16x8*)&Bl[br];
    }
    #pragma unroll
    for (int fi = 0; fi < 2; ++fi)
      #pragma unroll
      for (int fj = 0; fj < 4; ++fj) {
        MFMA(acc[fi][fj], ah[fi], bh[fj]);
        MFMA(acc[fi][fj], ah[fi], bl[fj]);
        MFMA(acc[fi][fj], al[fi], bh[fj]);
      }
    __syncthreads();
  }
  const int crow = (lane >> 4) * 4, ccol = lane & 15;
  #pragma unroll
  for (int fi = 0; fi < 2; ++fi)
    #pragma unroll
    for (int fj = 0; fj < 4; ++fj) {
      int row = m0 + wr * 32 + fi * 16 + crow;
      int col = n0 + wc * 64 + fj * 16 + ccol;
      #pragma unroll
      for (int r = 0; r < 4; ++r)
        Ob[(size_t)(row + r) * N_SEQ + col] = acc[fi][fj][r] + bias[row + r];
    }
}

// ---------------------------------------------------------------------------
extern "C" void kernel_launch(void* const* d_in, const int* in_sizes, int n_in,
                              void* d_out, int out_size, void* d_ws, size_t ws_size,
                              hipStream_t stream) {
  const float* x     = (const float*)d_in[0];
  const float* w_q   = (const float*)d_in[1];
  const float* w_kv  = (const float*)d_in[2];
  const float* w_out = (const float*)d_in[3];
  const float* b_out = (const float*)d_in[4];
  float* out = (float*)d_out;

  float* q_buf  = (float*)d_ws;                                  // 2*512*3584
  float* kv_buf = q_buf + (size_t)BATCH * INNER * N_SEQ;         // 2*1024*512
  float* ao_buf = kv_buf + (size_t)BATCH * 2 * INNER * LG;       // 2*512*3584
  // ao_buf doubles as split-K partial storage (3 x 1,048,576 floats) for
  // gemm_kv; consumed by kv_reduce before attn writes ao_buf.

  gemm_q   <<<dim3(28, 4, 2),  256, 0, stream>>>(w_q, x, q_buf);
  gemm_kv  <<<dim3(8, 8, 8),   256, 0, stream>>>(w_kv, x, kv_buf, ao_buf);
  kv_reduce<<<dim3(1024),      256, 0, stream>>>(kv_buf, ao_buf);
  attn     <<<dim3(28, 32),    256, 0, stream>>>(q_buf, kv_buf, ao_buf);
  gemm_out <<<dim3(28, 4, 2),  256, 0, stream>>>(w_out, ao_buf, b_out, out);
}

// Round 10
// 413.228 us; speedup vs baseline: 1.6123x; 1.1687x over previous
//
#include <hip/hip_runtime.h>
#include <cmath>

#define DIM 256
#define N_SEQ 3584
#define INNER 512
#define HEADS 8
#define DHEAD 64
#define LG 512       // downsampled K/V length
#define BATCH 2

typedef __attribute__((ext_vector_type(8))) short bf16x8;   // 8 bf16 = 4 VGPR
typedef __attribute__((ext_vector_type(4))) float f32x4;

// RNE fp32 -> bf16 (bit pattern)
static __device__ __forceinline__ unsigned short f2b(float v) {
  unsigned u = __float_as_uint(v);
  u = u + 0x7fffu + ((u >> 16) & 1u);
  return (unsigned short)(u >> 16);
}
static __device__ __forceinline__ float b2f(unsigned short h) {
  return __uint_as_float((unsigned)h << 16);
}

#define MFMA(d, a, b) d = __builtin_amdgcn_mfma_f32_16x16x32_bf16(a, b, d, 0, 0, 0)

// ---------------------------------------------------------------------------
// GEMM 1 (split-bf16 MFMA): Q = w_q (512x256) @ x[b] (256x3584)  [r8: PASS]
// ---------------------------------------------------------------------------
__global__ __launch_bounds__(256) void gemm_q(const float* __restrict__ W,
                                              const float* __restrict__ X,
                                              float* __restrict__ Q) {
  const int b  = blockIdx.z;
  const int n0 = blockIdx.x * 128;
  const int m0 = blockIdx.y * 128;
  const float* Xb = X + (size_t)b * DIM * N_SEQ;
  float* Qb = Q + (size_t)b * INNER * N_SEQ;
  __shared__ unsigned short Ah[128 * 40], Al[128 * 40];
  __shared__ unsigned short Bh[128 * 40], Bl[128 * 40];
  const int tid = threadIdx.x;
  const int lane = tid & 63, wid = tid >> 6;
  const int wr = wid >> 1, wc = wid & 1;
  const int lr = lane & 15, lk = (lane >> 4) * 8;

  f32x4 acc[4][4] = {};

  for (int k0 = 0; k0 < DIM; k0 += 32) {
    for (int i = tid; i < 4096; i += 256) {          // A tile 128x32
      int kk = i & 31, mm = i >> 5;
      float v = W[(size_t)(m0 + mm) * DIM + k0 + kk];
      unsigned short h = f2b(v);
      Ah[mm * 40 + kk] = h; Al[mm * 40 + kk] = f2b(v - b2f(h));
    }
    for (int i = tid; i < 4096; i += 256) {          // B tile 32x128 -> Bt[n][k]
      int nn = i & 127, kk = i >> 7;
      float v = Xb[(size_t)(k0 + kk) * N_SEQ + n0 + nn];
      unsigned short h = f2b(v);
      Bh[nn * 40 + kk] = h; Bl[nn * 40 + kk] = f2b(v - b2f(h));
    }
    __syncthreads();
    bf16x8 ah[4], al[4], bh[4], bl[4];
    #pragma unroll
    for (int f = 0; f < 4; ++f) {
      int ar = (wr * 64 + f * 16 + lr) * 40 + lk;
      ah[f] = *(const bf16x8*)&Ah[ar]; al[f] = *(const bf16x8*)&Al[ar];
      int br = (wc * 64 + f * 16 + lr) * 40 + lk;
      bh[f] = *(const bf16x8*)&Bh[br]; bl[f] = *(const bf16x8*)&Bl[br];
    }
    #pragma unroll
    for (int fi = 0; fi < 4; ++fi)
      #pragma unroll
      for (int fj = 0; fj < 4; ++fj) {
        MFMA(acc[fi][fj], ah[fi], bh[fj]);
        MFMA(acc[fi][fj], ah[fi], bl[fj]);
        MFMA(acc[fi][fj], al[fi], bh[fj]);
      }
    __syncthreads();
  }
  const int crow = (lane >> 4) * 4, ccol = lane & 15;
  #pragma unroll
  for (int fi = 0; fi < 4; ++fi)
    #pragma unroll
    for (int fj = 0; fj < 4; ++fj) {
      int row = m0 + wr * 64 + fi * 16 + crow;
      int col = n0 + wc * 64 + fj * 16 + ccol;
      #pragma unroll
      for (int r = 0; r < 4; ++r)
        Qb[(size_t)(row + r) * N_SEQ + col] = acc[fi][fj][r];
    }
}

// ---------------------------------------------------------------------------
// GEMM 2 (split-bf16 MFMA, split-K x4)  [r8: PASS]
// ---------------------------------------------------------------------------
__global__ __launch_bounds__(256) void gemm_kv(const float* __restrict__ Wkv,
                                               const float* __restrict__ X,
                                               float* __restrict__ KVp,
                                               float* __restrict__ Pbuf) {
  const int bz = blockIdx.z;
  const int b = bz >> 2, kc = bz & 3;
  const int l0 = blockIdx.x * 64;
  const int m0 = blockIdx.y * 128;
  const int c0 = kc * 64;
  const float* Xb = X + (size_t)b * DIM * N_SEQ;
  __shared__ unsigned short Ah[128 * 72], Al[128 * 72];
  __shared__ unsigned short Bh[64 * 72],  Bl[64 * 72];
  const int tid = threadIdx.x;
  const int lane = tid & 63, wid = tid >> 6;
  const int wr = wid >> 1, wc = wid & 1;
  const int lr = lane & 15, lk = (lane >> 4) * 8;

  for (int i = tid; i < 1024; i += 256) {
    int rr = i >> 3, kk = 56 + (i & 7);
    Ah[rr * 72 + kk] = 0; Al[rr * 72 + kk] = 0;
    if (rr < 64) { Bh[rr * 72 + kk] = 0; Bl[rr * 72 + kk] = 0; }
  }

  f32x4 acc[4][2] = {};

  for (int s = 0; s < 8; ++s) {
    const int kbase = c0 * 7 + s * 56;
    const int cbase = c0 + s * 8;
    for (int i = tid; i < 7168; i += 256) {
      int kk = i % 56, mm = i / 56;
      float v = Wkv[(size_t)(m0 + mm) * 1792 + kbase + kk];
      unsigned short h = f2b(v);
      Ah[mm * 72 + kk] = h; Al[mm * 72 + kk] = f2b(v - b2f(h));
    }
    for (int i = tid; i < 3584; i += 256) {
      int ch = i / 448, t = i % 448;
      int l = t / 7, j = t - (t / 7) * 7;
      float v = Xb[(size_t)(cbase + ch) * N_SEQ + l0 * 7 + t];
      unsigned short h = f2b(v);
      int idx = l * 72 + ch * 7 + j;
      Bh[idx] = h; Bl[idx] = f2b(v - b2f(h));
    }
    __syncthreads();
    #pragma unroll
    for (int kh = 0; kh < 2; ++kh) {
      const int ko = kh * 32 + lk;
      bf16x8 ah[4], al[4], bh[2], bl[2];
      #pragma unroll
      for (int f = 0; f < 4; ++f) {
        int ar = (wr * 64 + f * 16 + lr) * 72 + ko;
        ah[f] = *(const bf16x8*)&Ah[ar]; al[f] = *(const bf16x8*)&Al[ar];
      }
      #pragma unroll
      for (int f = 0; f < 2; ++f) {
        int br = (wc * 32 + f * 16 + lr) * 72 + ko;
        bh[f] = *(const bf16x8*)&Bh[br]; bl[f] = *(const bf16x8*)&Bl[br];
      }
      #pragma unroll
      for (int fi = 0; fi < 4; ++fi)
        #pragma unroll
        for (int fj = 0; fj < 2; ++fj) {
          MFMA(acc[fi][fj], ah[fi], bh[fj]);
          MFMA(acc[fi][fj], ah[fi], bl[fj]);
          MFMA(acc[fi][fj], al[fi], bh[fj]);
        }
    }
    __syncthreads();
  }

  float* dst = (kc == 0) ? KVp : (Pbuf + (size_t)(kc - 1) * (BATCH * 2 * INNER * LG));
  dst += (size_t)b * 2 * INNER * LG;
  const int crow = (lane >> 4) * 4, ccol = lane & 15;
  #pragma unroll
  for (int fi = 0; fi < 4; ++fi)
    #pragma unroll
    for (int fj = 0; fj < 2; ++fj) {
      int row = m0 + wr * 64 + fi * 16 + crow;
      int col = l0 + wc * 32 + fj * 16 + ccol;
      #pragma unroll
      for (int r = 0; r < 4; ++r)
        dst[(size_t)(row + r) * LG + col] = acc[fi][fj][r];
    }
}

// reduce: kv += p1 + p2 + p3
__global__ __launch_bounds__(256) void kv_reduce(float* __restrict__ KVp,
                                                 const float* __restrict__ Pbuf) {
  const size_t i = ((size_t)blockIdx.x * 256 + threadIdx.x) * 4;
  const size_t n1 = (size_t)BATCH * 2 * INNER * LG;
  float4 a  = *(const float4*)&KVp[i];
  float4 p1 = *(const float4*)&Pbuf[i];
  float4 p2 = *(const float4*)&Pbuf[n1 + i];
  float4 p3 = *(const float4*)&Pbuf[2 * n1 + i];
  a.x += p1.x + p2.x + p3.x;
  a.y += p1.y + p2.y + p3.y;
  a.z += p1.z + p2.z + p3.z;
  a.w += p1.w + p2.w + p3.w;
  *(float4*)&KVp[i] = a;
}

// ---------------------------------------------------------------------------
// Attention v3: split-bf16 MFMA flash attention.
// 4 waves x 16 q-rows; K/V tiles of 64; per wave-tile 24 QK + 24 PV MFMA.
// K transposed into LDS [j][d] with XOR swizzle ((row&7)<<3 on col, keeps
// b128 runs); V natural [dv][j] (= B^T for PV). P via per-wave LDS (hi/lo).
// Softmax entirely intra-16-lane-group (each wave owns complete rows).
// ---------------------------------------------------------------------------
__global__ __launch_bounds__(256) void attn(const float* __restrict__ Q,
                                            const float* __restrict__ KV,
                                            float* __restrict__ AO) {
  const int combo = blockIdx.y;
  const int a = combo >> 4, e = (combo >> 3) & 1, h = combo & 7;
  const int r0 = blockIdx.x * 64;
  const float* Qp = Q  + ((size_t)a * INNER + h * DHEAD) * N_SEQ;
  const float* Kp = KV + ((size_t)e * 2 * INNER + h * DHEAD) * LG;
  const float* Vp = KV + ((size_t)e * 2 * INNER + INNER + h * DHEAD) * LG;
  float* Op = AO + ((size_t)a * INNER + h * DHEAD) * N_SEQ;

  __shared__ __align__(16) unsigned char smem[55296];
  unsigned short* KQh = (unsigned short*)smem;        // [64*72] Q then K (hi)
  unsigned short* KQl = KQh + 4608;                   // lo plane
  unsigned short* Vh_ = KQh + 2 * 4608;               // V hi [dv][j]
  unsigned short* Vl_ = KQh + 3 * 4608;               // V lo
  unsigned short* Pb  = KQh + 4 * 4608;               // [4 waves][2][16*72]
  float* Os = (float*)smem;                           // [64][68] epilogue

  const int tid = threadIdx.x;
  const int lane = tid & 63, w = tid >> 6;
  const int lr = lane & 15, lg = lane >> 4;
  const int lk = lg * 8;
  unsigned short* Pwh = Pb + w * 2304;
  unsigned short* Pwl = Pwh + 1152;

  // ---- stage Q [r][d] split+swizzled (dd-pairs packed into b32 writes)
  for (int i = tid; i < 2048; i += 256) {
    int dp = i >> 6, r2 = i & 63, dd = dp * 2;
    int r = r0 + r2;
    int c = r / 7, p = r - c * 7;
    size_t nq = (size_t)(c * 14 + e * 7 + p);
    float q0 = Qp[(size_t)dd * N_SEQ + nq];
    float q1 = Qp[(size_t)(dd + 1) * N_SEQ + nq];
    unsigned short h0 = f2b(q0), h1 = f2b(q1);
    unsigned short u0 = f2b(q0 - b2f(h0)), u1 = f2b(q1 - b2f(h1));
    int col = dd ^ ((r2 & 7) << 3);   // even -> b32-aligned
    *(unsigned int*)&KQh[r2 * 72 + col] = (unsigned)h0 | ((unsigned)h1 << 16);
    *(unsigned int*)&KQl[r2 * 72 + col] = (unsigned)u0 | ((unsigned)u1 << 16);
  }
  __syncthreads();
  // Q a-frags to registers (rows w*16+lr)
  bf16x8 qh[2], ql[2];
  {
    int base = (w * 16 + lr) * 72;
    int sw = (lr & 7) << 3;
    qh[0] = *(const bf16x8*)&KQh[base + ((0 + lk) ^ sw)];
    qh[1] = *(const bf16x8*)&KQh[base + ((32 + lk) ^ sw)];
    ql[0] = *(const bf16x8*)&KQl[base + ((0 + lk) ^ sw)];
    ql[1] = *(const bf16x8*)&KQl[base + ((32 + lk) ^ sw)];
  }

  f32x4 oacc[4] = {};
  float m_run[4] = {-INFINITY, -INFINITY, -INFINITY, -INFINITY};
  float l_run[4] = {0.f, 0.f, 0.f, 0.f};
  const float scale = 0.125f;

  for (int t = 0; t < 8; ++t) {
    const int j0 = t * 64;
    __syncthreads();          // Q-frags / prev tile consumed
    // stage K transposed [j][d] (swizzled, dd-pairs packed)
    for (int i = tid; i < 2048; i += 256) {
      int dp = i >> 6, jj = i & 63, dd = dp * 2;
      float k0v = Kp[(size_t)dd * LG + j0 + jj];
      float k1v = Kp[(size_t)(dd + 1) * LG + j0 + jj];
      unsigned short h0 = f2b(k0v), h1 = f2b(k1v);
      unsigned short u0 = f2b(k0v - b2f(h0)), u1 = f2b(k1v - b2f(h1));
      int col = dd ^ ((jj & 7) << 3);
      *(unsigned int*)&KQh[jj * 72 + col] = (unsigned)h0 | ((unsigned)h1 << 16);
      *(unsigned int*)&KQl[jj * 72 + col] = (unsigned)u0 | ((unsigned)u1 << 16);
    }
    // stage V natural [dv][j] (jj-pairs packed, float2 loads)
    for (int i = tid; i < 2048; i += 256) {
      int dd = i >> 5, jp = i & 31;
      float2 vv = *(const float2*)&Vp[(size_t)dd * LG + j0 + jp * 2];
      unsigned short h0 = f2b(vv.x), h1 = f2b(vv.y);
      unsigned short u0 = f2b(vv.x - b2f(h0)), u1 = f2b(vv.y - b2f(h1));
      *(unsigned int*)&Vh_[dd * 72 + jp * 2] = (unsigned)h0 | ((unsigned)h1 << 16);
      *(unsigned int*)&Vl_[dd * 72 + jp * 2] = (unsigned)u0 | ((unsigned)u1 << 16);
    }
    __syncthreads();

    // ---- QK^T: S[16 rows][64 j] per wave
    f32x4 sacc[4] = {};
    #pragma unroll
    for (int ks = 0; ks < 2; ++ks) {
      #pragma unroll
      for (int f = 0; f < 4; ++f) {
        int off = (f * 16 + lr) * 72 + ((ks * 32 + lk) ^ ((lr & 7) << 3));
        bf16x8 kh = *(const bf16x8*)&KQh[off];
        bf16x8 kl = *(const bf16x8*)&KQl[off];
        MFMA(sacc[f], qh[ks], kh);
        MFMA(sacc[f], qh[ks], kl);
        MFMA(sacc[f], ql[ks], kh);
      }
    }

    // ---- online softmax (lane: 4 rows (reg) x 4 j (frag))
    float s[4][4];   // [f][r]
    float corr[4];
    #pragma unroll
    for (int r = 0; r < 4; ++r) {
      float mx = -INFINITY;
      #pragma unroll
      for (int f = 0; f < 4; ++f) { s[f][r] = sacc[f][r] * scale; mx = fmaxf(mx, s[f][r]); }
      mx = fmaxf(mx, __shfl_xor(mx, 1));
      mx = fmaxf(mx, __shfl_xor(mx, 2));
      mx = fmaxf(mx, __shfl_xor(mx, 4));
      mx = fmaxf(mx, __shfl_xor(mx, 8));
      float mn = fmaxf(m_run[r], mx);
      corr[r] = __expf(m_run[r] - mn);
      m_run[r] = mn;
      float ls = 0.f;
      #pragma unroll
      for (int f = 0; f < 4; ++f) { s[f][r] = __expf(s[f][r] - mn); ls += s[f][r]; }
      ls += __shfl_xor(ls, 1); ls += __shfl_xor(ls, 2);
      ls += __shfl_xor(ls, 4); ls += __shfl_xor(ls, 8);
      l_run[r] = l_run[r] * corr[r] + ls;
    }

    // ---- write P (split) to per-wave LDS, row-keyed swizzle
    #pragma unroll
    for (int r = 0; r < 4; ++r) {
      int prow = lg * 4 + r;
      int sw = (prow & 7) << 3;
      #pragma unroll
      for (int f = 0; f < 4; ++f) {
        int col = (16 * f + lr) ^ sw;
        unsigned short ph = f2b(s[f][r]);
        Pwh[prow * 72 + col] = ph;
        Pwl[prow * 72 + col] = f2b(s[f][r] - b2f(ph));
      }
    }
    __syncthreads();   // P visible (cross-lane) + all QK reads of K done

    // ---- rescale O
    #pragma unroll
    for (int f = 0; f < 4; ++f)
      #pragma unroll
      for (int r = 0; r < 4; ++r)
        oacc[f][r] *= corr[r];

    // ---- PV: O[16 rows][64 dv] += P . V
    #pragma unroll
    for (int ks = 0; ks < 2; ++ks) {
      int pbase = lr * 72 + ((ks * 32 + lk) ^ ((lr & 7) << 3));
      bf16x8 ph = *(const bf16x8*)&Pwh[pbase];
      bf16x8 pl = *(const bf16x8*)&Pwl[pbase];
      #pragma unroll
      for (int f = 0; f < 4; ++f) {
        int off = (f * 16 + lr) * 72 + ks * 32 + lk;
        bf16x8 vh = *(const bf16x8*)&Vh_[off];
        bf16x8 vl = *(const bf16x8*)&Vl_[off];
        MFMA(oacc[f], ph, vh);
        MFMA(oacc[f], ph, vl);
        MFMA(oacc[f], pl, vh);
      }
    }
  }

  // ---- epilogue: normalize, transpose via LDS (K region is dead), write out
  float rl[4];
  #pragma unroll
  for (int r = 0; r < 4; ++r) rl[r] = 1.0f / l_run[r];
  #pragma unroll
  for (int f = 0; f < 4; ++f)
    #pragma unroll
    for (int r = 0; r < 4; ++r)
      Os[(w * 16 + lg * 4 + r) * 68 + 16 * f + lr] = oacc[f][r] * rl[r];
  __syncthreads();
  for (int i = tid; i < 4096; i += 256) {
    int dd = i >> 6, r2 = i & 63;
    int r = r0 + r2;
    int c = r / 7, p = r - c * 7;
    Op[(size_t)dd * N_SEQ + (c * 14 + e * 7 + p)] = Os[r2 * 68 + dd];
  }
}

// ---------------------------------------------------------------------------
// GEMM 3 (split-bf16 MFMA)  [r8: PASS]
// ---------------------------------------------------------------------------
__global__ __launch_bounds__(256) void gemm_out(const float* __restrict__ W,
                                                const float* __restrict__ AO,
                                                const float* __restrict__ bias,
                                                float* __restrict__ Out) {
  const int b  = blockIdx.z;
  const int n0 = blockIdx.x * 128;
  const int m0 = blockIdx.y * 64;
  const float* Ab = AO + (size_t)b * INNER * N_SEQ;
  float* Ob = Out + (size_t)b * DIM * N_SEQ;
  __shared__ unsigned short Ah[64 * 40], Al[64 * 40];
  __shared__ unsigned short Bh[128 * 40], Bl[128 * 40];
  const int tid = threadIdx.x;
  const int lane = tid & 63, wid = tid >> 6;
  const int wr = wid >> 1, wc = wid & 1;
  const int lr = lane & 15, lk = (lane >> 4) * 8;

  f32x4 acc[2][4] = {};

  for (int k0 = 0; k0 < INNER; k0 += 32) {
    for (int i = tid; i < 2048; i += 256) {
      int kk = i & 31, mm = i >> 5;
      float v = W[(size_t)(m0 + mm) * INNER + k0 + kk];
      unsigned short h = f2b(v);
      Ah[mm * 40 + kk] = h; Al[mm * 40 + kk] = f2b(v - b2f(h));
    }
    for (int i = tid; i < 4096; i += 256) {
      int nn = i & 127, kk = i >> 7;
      float v = Ab[(size_t)(k0 + kk) * N_SEQ + n0 + nn];
      unsigned short h = f2b(v);
      Bh[nn * 40 + kk] = h; Bl[nn * 40 + kk] = f2b(v - b2f(h));
    }
    __syncthreads();
    bf16x8 ah[2], al[2], bh[4], bl[4];
    #pragma unroll
    for (int f = 0; f < 2; ++f) {
      int ar = (wr * 32 + f * 16 + lr) * 40 + lk;
      ah[f] = *(const bf16x8*)&Ah[ar]; al[f] = *(const bf16x8*)&Al[ar];
    }
    #pragma unroll
    for (int f = 0; f < 4; ++f) {
      int br = (wc * 64 + f * 16 + lr) * 40 + lk;
      bh[f] = *(const bf16x8*)&Bh[br]; bl[f] = *(const bf16x8*)&Bl[br];
    }
    #pragma unroll
    for (int fi = 0; fi < 2; ++fi)
      #pragma unroll
      for (int fj = 0; fj < 4; ++fj) {
        MFMA(acc[fi][fj], ah[fi], bh[fj]);
        MFMA(acc[fi][fj], ah[fi], bl[fj]);
        MFMA(acc[fi][fj], al[fi], bh[fj]);
      }
    __syncthreads();
  }
  const int crow = (lane >> 4) * 4, ccol = lane & 15;
  #pragma unroll
  for (int fi = 0; fi < 2; ++fi)
    #pragma unroll
    for (int fj = 0; fj < 4; ++fj) {
      int row = m0 + wr * 32 + fi * 16 + crow;
      int col = n0 + wc * 64 + fj * 16 + ccol;
      #pragma unroll
      for (int r = 0; r < 4; ++r)
        Ob[(size_t)(row + r) * N_SEQ + col] = acc[fi][fj][r] + bias[row + r];
    }
}

// ---------------------------------------------------------------------------
extern "C" void kernel_launch(void* const* d_in, const int* in_sizes, int n_in,
                              void* d_out, int out_size, void* d_ws, size_t ws_size,
                              hipStream_t stream) {
  const float* x     = (const float*)d_in[0];
  const float* w_q   = (const float*)d_in[1];
  const float* w_kv  = (const float*)d_in[2];
  const float* w_out = (const float*)d_in[3];
  const float* b_out = (const float*)d_in[4];
  float* out = (float*)d_out;

  float* q_buf  = (float*)d_ws;                                  // 2*512*3584
  float* kv_buf = q_buf + (size_t)BATCH * INNER * N_SEQ;         // 2*1024*512
  float* ao_buf = kv_buf + (size_t)BATCH * 2 * INNER * LG;       // 2*512*3584

  gemm_q   <<<dim3(28, 4, 2),  256, 0, stream>>>(w_q, x, q_buf);
  gemm_kv  <<<dim3(8, 8, 8),   256, 0, stream>>>(w_kv, x, kv_buf, ao_buf);
  kv_reduce<<<dim3(1024),      256, 0, stream>>>(kv_buf, ao_buf);
  attn     <<<dim3(28, 32),    256, 0, stream>>>(q_buf, kv_buf, ao_buf);
  gemm_out <<<dim3(28, 4, 2),  256, 0, stream>>>(w_out, ao_buf, b_out, out);
}

// Round 11
// 348.334 us; speedup vs baseline: 1.9127x; 1.1863x over previous
//
#include <hip/hip_runtime.h>
#include <cmath>

#define DIM 256
#define N_SEQ 3584
#define INNER 512
#define HEADS 8
#define DHEAD 64
#define LG 512       // downsampled K/V length
#define BATCH 2

typedef __attribute__((ext_vector_type(8))) short bf16x8;   // 8 bf16 = 4 VGPR
typedef __attribute__((ext_vector_type(4))) float f32x4;

// RNE fp32 -> bf16 (bit pattern)
static __device__ __forceinline__ unsigned short f2b(float v) {
  unsigned u = __float_as_uint(v);
  u = u + 0x7fffu + ((u >> 16) & 1u);
  return (unsigned short)(u >> 16);
}
static __device__ __forceinline__ float b2f(unsigned short h) {
  return __uint_as_float((unsigned)h << 16);
}

#define MFMA(d, a, b) d = __builtin_amdgcn_mfma_f32_16x16x32_bf16(a, b, d, 0, 0, 0)

// ---------------------------------------------------------------------------
// GEMM 1 (split-bf16 MFMA): Q = w_q (512x256) @ x[b] (256x3584)  [r8: PASS]
// ---------------------------------------------------------------------------
__global__ __launch_bounds__(256) void gemm_q(const float* __restrict__ W,
                                              const float* __restrict__ X,
                                              float* __restrict__ Q) {
  const int b  = blockIdx.z;
  const int n0 = blockIdx.x * 128;
  const int m0 = blockIdx.y * 128;
  const float* Xb = X + (size_t)b * DIM * N_SEQ;
  float* Qb = Q + (size_t)b * INNER * N_SEQ;
  __shared__ unsigned short Ah[128 * 40], Al[128 * 40];
  __shared__ unsigned short Bh[128 * 40], Bl[128 * 40];
  const int tid = threadIdx.x;
  const int lane = tid & 63, wid = tid >> 6;
  const int wr = wid >> 1, wc = wid & 1;
  const int lr = lane & 15, lk = (lane >> 4) * 8;

  f32x4 acc[4][4] = {};

  for (int k0 = 0; k0 < DIM; k0 += 32) {
    for (int i = tid; i < 4096; i += 256) {          // A tile 128x32
      int kk = i & 31, mm = i >> 5;
      float v = W[(size_t)(m0 + mm) * DIM + k0 + kk];
      unsigned short h = f2b(v);
      Ah[mm * 40 + kk] = h; Al[mm * 40 + kk] = f2b(v - b2f(h));
    }
    for (int i = tid; i < 4096; i += 256) {          // B tile 32x128 -> Bt[n][k]
      int nn = i & 127, kk = i >> 7;
      float v = Xb[(size_t)(k0 + kk) * N_SEQ + n0 + nn];
      unsigned short h = f2b(v);
      Bh[nn * 40 + kk] = h; Bl[nn * 40 + kk] = f2b(v - b2f(h));
    }
    __syncthreads();
    bf16x8 ah[4], al[4], bh[4], bl[4];
    #pragma unroll
    for (int f = 0; f < 4; ++f) {
      int ar = (wr * 64 + f * 16 + lr) * 40 + lk;
      ah[f] = *(const bf16x8*)&Ah[ar]; al[f] = *(const bf16x8*)&Al[ar];
      int br = (wc * 64 + f * 16 + lr) * 40 + lk;
      bh[f] = *(const bf16x8*)&Bh[br]; bl[f] = *(const bf16x8*)&Bl[br];
    }
    #pragma unroll
    for (int fi = 0; fi < 4; ++fi)
      #pragma unroll
      for (int fj = 0; fj < 4; ++fj) {
        MFMA(acc[fi][fj], ah[fi], bh[fj]);
        MFMA(acc[fi][fj], ah[fi], bl[fj]);
        MFMA(acc[fi][fj], al[fi], bh[fj]);
      }
    __syncthreads();
  }
  const int crow = (lane >> 4) * 4, ccol = lane & 15;
  #pragma unroll
  for (int fi = 0; fi < 4; ++fi)
    #pragma unroll
    for (int fj = 0; fj < 4; ++fj) {
      int row = m0 + wr * 64 + fi * 16 + crow;
      int col = n0 + wc * 64 + fj * 16 + ccol;
      #pragma unroll
      for (int r = 0; r < 4; ++r)
        Qb[(size_t)(row + r) * N_SEQ + col] = acc[fi][fj][r];
    }
}

// ---------------------------------------------------------------------------
// GEMM 2 (split-bf16 MFMA, split-K x4)  [r8: PASS]
// partial(kc=0) -> kv_buf; kc=1..3 -> Pbuf slabs (summed by kv_prep).
// ---------------------------------------------------------------------------
__global__ __launch_bounds__(256) void gemm_kv(const float* __restrict__ Wkv,
                                               const float* __restrict__ X,
                                               float* __restrict__ KVp,
                                               float* __restrict__ Pbuf) {
  const int bz = blockIdx.z;
  const int b = bz >> 2, kc = bz & 3;
  const int l0 = blockIdx.x * 64;
  const int m0 = blockIdx.y * 128;
  const int c0 = kc * 64;
  const float* Xb = X + (size_t)b * DIM * N_SEQ;
  __shared__ unsigned short Ah[128 * 72], Al[128 * 72];
  __shared__ unsigned short Bh[64 * 72],  Bl[64 * 72];
  const int tid = threadIdx.x;
  const int lane = tid & 63, wid = tid >> 6;
  const int wr = wid >> 1, wc = wid & 1;
  const int lr = lane & 15, lk = (lane >> 4) * 8;

  for (int i = tid; i < 1024; i += 256) {
    int rr = i >> 3, kk = 56 + (i & 7);
    Ah[rr * 72 + kk] = 0; Al[rr * 72 + kk] = 0;
    if (rr < 64) { Bh[rr * 72 + kk] = 0; Bl[rr * 72 + kk] = 0; }
  }

  f32x4 acc[4][2] = {};

  for (int s = 0; s < 8; ++s) {
    const int kbase = c0 * 7 + s * 56;
    const int cbase = c0 + s * 8;
    for (int i = tid; i < 7168; i += 256) {
      int kk = i % 56, mm = i / 56;
      float v = Wkv[(size_t)(m0 + mm) * 1792 + kbase + kk];
      unsigned short h = f2b(v);
      Ah[mm * 72 + kk] = h; Al[mm * 72 + kk] = f2b(v - b2f(h));
    }
    for (int i = tid; i < 3584; i += 256) {
      int ch = i / 448, t = i % 448;
      int l = t / 7, j = t - (t / 7) * 7;
      float v = Xb[(size_t)(cbase + ch) * N_SEQ + l0 * 7 + t];
      unsigned short h = f2b(v);
      int idx = l * 72 + ch * 7 + j;
      Bh[idx] = h; Bl[idx] = f2b(v - b2f(h));
    }
    __syncthreads();
    #pragma unroll
    for (int kh = 0; kh < 2; ++kh) {
      const int ko = kh * 32 + lk;
      bf16x8 ah[4], al[4], bh[2], bl[2];
      #pragma unroll
      for (int f = 0; f < 4; ++f) {
        int ar = (wr * 64 + f * 16 + lr) * 72 + ko;
        ah[f] = *(const bf16x8*)&Ah[ar]; al[f] = *(const bf16x8*)&Al[ar];
      }
      #pragma unroll
      for (int f = 0; f < 2; ++f) {
        int br = (wc * 32 + f * 16 + lr) * 72 + ko;
        bh[f] = *(const bf16x8*)&Bh[br]; bl[f] = *(const bf16x8*)&Bl[br];
      }
      #pragma unroll
      for (int fi = 0; fi < 4; ++fi)
        #pragma unroll
        for (int fj = 0; fj < 2; ++fj) {
          MFMA(acc[fi][fj], ah[fi], bh[fj]);
          MFMA(acc[fi][fj], ah[fi], bl[fj]);
          MFMA(acc[fi][fj], al[fi], bh[fj]);
        }
    }
    __syncthreads();
  }

  float* dst = (kc == 0) ? KVp : (Pbuf + (size_t)(kc - 1) * (BATCH * 2 * INNER * LG));
  dst += (size_t)b * 2 * INNER * LG;
  const int crow = (lane >> 4) * 4, ccol = lane & 15;
  #pragma unroll
  for (int fi = 0; fi < 4; ++fi)
    #pragma unroll
    for (int fj = 0; fj < 2; ++fj) {
      int row = m0 + wr * 64 + fi * 16 + crow;
      int col = l0 + wc * 32 + fj * 16 + ccol;
      #pragma unroll
      for (int r = 0; r < 4; ++r)
        dst[(size_t)(row + r) * LG + col] = acc[fi][fj][r];
    }
}

// ---------------------------------------------------------------------------
// kv_prep (NEW, replaces kv_reduce): sum 4 split-K partials; emit split-bf16
//   K pre-transposed [combo=e*8+h][j=512][d=64]  (transpose via LDS, 2-way banks)
//   V natural        [combo][d=64][j=512]
// r10 counters: attn's in-kernel fp32->bf16 transpose-staging was a 16-way
// bank conflict (26.3M/dispatch) + redundant per-tile conversion; hoist here.
// ---------------------------------------------------------------------------
__global__ __launch_bounds__(256) void kv_prep(const float* __restrict__ KVp,
                                               const float* __restrict__ Pbuf,
                                               unsigned short* __restrict__ Kh,
                                               unsigned short* __restrict__ Kl,
                                               unsigned short* __restrict__ Vh,
                                               unsigned short* __restrict__ Vl) {
  const int combo = blockIdx.y;           // e*8 + h
  const int e = combo >> 3, h = combo & 7;
  const int j0 = blockIdx.x * 64;
  const size_t n1 = (size_t)BATCH * 2 * INNER * LG;
  const size_t eoff = (size_t)e * 2 * INNER * LG;
  const float* s0 = KVp + eoff;
  const float* s1 = Pbuf + eoff;
  const float* s2 = Pbuf + n1 + eoff;
  const float* s3 = Pbuf + 2 * n1 + eoff;

  __shared__ float Ls[64 * 65];
  const int tid = threadIdx.x;

  // K rows m = h*64+d, cols j0+j -> LDS [d][j] (stride 65: 2-way banks)
  for (int i = tid; i < 4096; i += 256) {
    int d = i >> 6, j = i & 63;
    size_t idx = (size_t)(h * 64 + d) * LG + j0 + j;
    Ls[d * 65 + j] = s0[idx] + s1[idx] + s2[idx] + s3[idx];
  }
  __syncthreads();
  // write K transposed [j][d], split-bf16, b32-packed d-pairs (coalesced)
  unsigned short* kh = Kh + ((size_t)combo * LG + j0) * 64;
  unsigned short* kl = Kl + ((size_t)combo * LG + j0) * 64;
  for (int i = tid; i < 2048; i += 256) {
    int j = i >> 5, dp = i & 31;
    float v0 = Ls[(2 * dp) * 65 + j];
    float v1 = Ls[(2 * dp + 1) * 65 + j];
    unsigned short h0 = f2b(v0), h1 = f2b(v1);
    unsigned short u0 = f2b(v0 - b2f(h0)), u1 = f2b(v1 - b2f(h1));
    *(unsigned int*)&kh[j * 64 + 2 * dp] = (unsigned)h0 | ((unsigned)h1 << 16);
    *(unsigned int*)&kl[j * 64 + 2 * dp] = (unsigned)u0 | ((unsigned)u1 << 16);
  }

  // V rows m = INNER+h*64+d: natural copy+sum+convert (coalesced both sides)
  unsigned short* vh = Vh + (size_t)combo * 64 * LG;
  unsigned short* vl = Vl + (size_t)combo * 64 * LG;
  for (int i = tid; i < 2048; i += 256) {
    int d = i >> 5, jp = i & 31;
    size_t idx = (size_t)(INNER + h * 64 + d) * LG + j0 + jp * 2;
    float v0 = s0[idx] + s1[idx] + s2[idx] + s3[idx];
    float v1 = s0[idx + 1] + s1[idx + 1] + s2[idx + 1] + s3[idx + 1];
    unsigned short h0 = f2b(v0), h1 = f2b(v1);
    unsigned short u0 = f2b(v0 - b2f(h0)), u1 = f2b(v1 - b2f(h1));
    *(unsigned int*)&vh[(size_t)d * LG + j0 + jp * 2] = (unsigned)h0 | ((unsigned)h1 << 16);
    *(unsigned int*)&vl[(size_t)d * LG + j0 + jp * 2] = (unsigned)u0 | ((unsigned)u1 << 16);
  }
}

// ---------------------------------------------------------------------------
// Attention v4: split-bf16 MFMA flash attention, pre-converted K/V.
// Staging is now pure uint4 copies (global coalesced; LDS b128 uniform-bank).
// QK/softmax/PV/epilogue identical to v3 (passed r10).
// ---------------------------------------------------------------------------
__global__ __launch_bounds__(256) void attn(const float* __restrict__ Q,
                                            const unsigned short* __restrict__ Kh,
                                            const unsigned short* __restrict__ Kl,
                                            const unsigned short* __restrict__ Vh,
                                            const unsigned short* __restrict__ Vl,
                                            float* __restrict__ AO) {
  const int combo = blockIdx.y;
  const int a = combo >> 4, e = (combo >> 3) & 1, h = combo & 7;
  const int r0 = blockIdx.x * 64;
  const float* Qp = Q + ((size_t)a * INNER + h * DHEAD) * N_SEQ;
  float* Op = AO + ((size_t)a * INNER + h * DHEAD) * N_SEQ;
  const int cmb = e * 8 + h;
  const unsigned short* KTh = Kh + (size_t)cmb * LG * 64;   // [j][d]
  const unsigned short* KTl = Kl + (size_t)cmb * LG * 64;
  const unsigned short* VNh = Vh + (size_t)cmb * 64 * LG;   // [d][j]
  const unsigned short* VNl = Vl + (size_t)cmb * 64 * LG;

  __shared__ __align__(16) unsigned char smem[55296];
  unsigned short* KQh = (unsigned short*)smem;        // [64*72] Q then K (hi)
  unsigned short* KQl = KQh + 4608;                   // lo plane
  unsigned short* Vh_ = KQh + 2 * 4608;               // V hi [dv][j]
  unsigned short* Vl_ = KQh + 3 * 4608;               // V lo
  unsigned short* Pb  = KQh + 4 * 4608;               // [4 waves][2][16*72]
  float* Os = (float*)smem;                           // [64][68] epilogue

  const int tid = threadIdx.x;
  const int lane = tid & 63, w = tid >> 6;
  const int lr = lane & 15, lg = lane >> 4;
  const int lk = lg * 8;
  unsigned short* Pwh = Pb + w * 2304;
  unsigned short* Pwl = Pwh + 1152;

  // ---- stage Q [r][d] split+swizzled (once per block; fp32 source)
  for (int i = tid; i < 2048; i += 256) {
    int dp = i >> 6, r2 = i & 63, dd = dp * 2;
    int r = r0 + r2;
    int c = r / 7, p = r - c * 7;
    size_t nq = (size_t)(c * 14 + e * 7 + p);
    float q0 = Qp[(size_t)dd * N_SEQ + nq];
    float q1 = Qp[(size_t)(dd + 1) * N_SEQ + nq];
    unsigned short h0 = f2b(q0), h1 = f2b(q1);
    unsigned short u0 = f2b(q0 - b2f(h0)), u1 = f2b(q1 - b2f(h1));
    int col = dd ^ ((r2 & 7) << 3);   // even -> b32-aligned
    *(unsigned int*)&KQh[r2 * 72 + col] = (unsigned)h0 | ((unsigned)h1 << 16);
    *(unsigned int*)&KQl[r2 * 72 + col] = (unsigned)u0 | ((unsigned)u1 << 16);
  }
  __syncthreads();
  // Q a-frags to registers (rows w*16+lr)
  bf16x8 qh[2], ql[2];
  {
    int base = (w * 16 + lr) * 72;
    int sw = (lr & 7) << 3;
    qh[0] = *(const bf16x8*)&KQh[base + ((0 + lk) ^ sw)];
    qh[1] = *(const bf16x8*)&KQh[base + ((32 + lk) ^ sw)];
    ql[0] = *(const bf16x8*)&KQl[base + ((0 + lk) ^ sw)];
    ql[1] = *(const bf16x8*)&KQl[base + ((32 + lk) ^ sw)];
  }

  f32x4 oacc[4] = {};
  float m_run[4] = {-INFINITY, -INFINITY, -INFINITY, -INFINITY};
  float l_run[4] = {0.f, 0.f, 0.f, 0.f};
  const float scale = 0.125f;

  for (int t = 0; t < 8; ++t) {
    const int j0 = t * 64;
    __syncthreads();          // Q-frags read / prev tile fully consumed
    // stage K [j][d] bf16 copy with swizzle (uniform-bank b128 writes)
    for (int i = tid; i < 512; i += 256) {
      int row = i >> 3, ch = i & 7;
      int col = (ch * 8) ^ ((row & 7) << 3);
      *(uint4*)&KQh[row * 72 + col] =
          *(const uint4*)&KTh[(size_t)(j0 + row) * 64 + ch * 8];
      *(uint4*)&KQl[row * 72 + col] =
          *(const uint4*)&KTl[(size_t)(j0 + row) * 64 + ch * 8];
    }
    // stage V [d][j] bf16 copy, no swizzle
    for (int i = tid; i < 512; i += 256) {
      int d = i >> 3, ch = i & 7;
      *(uint4*)&Vh_[d * 72 + ch * 8] =
          *(const uint4*)&VNh[(size_t)d * LG + j0 + ch * 8];
      *(uint4*)&Vl_[d * 72 + ch * 8] =
          *(const uint4*)&VNl[(size_t)d * LG + j0 + ch * 8];
    }
    __syncthreads();

    // ---- QK^T: S[16 rows][64 j] per wave
    f32x4 sacc[4] = {};
    #pragma unroll
    for (int ks = 0; ks < 2; ++ks) {
      #pragma unroll
      for (int f = 0; f < 4; ++f) {
        int off = (f * 16 + lr) * 72 + ((ks * 32 + lk) ^ ((lr & 7) << 3));
        bf16x8 kh = *(const bf16x8*)&KQh[off];
        bf16x8 kl = *(const bf16x8*)&KQl[off];
        MFMA(sacc[f], qh[ks], kh);
        MFMA(sacc[f], qh[ks], kl);
        MFMA(sacc[f], ql[ks], kh);
      }
    }

    // ---- online softmax (lane: 4 rows (reg) x 4 j (frag))
    float s[4][4];   // [f][r]
    float corr[4];
    #pragma unroll
    for (int r = 0; r < 4; ++r) {
      float mx = -INFINITY;
      #pragma unroll
      for (int f = 0; f < 4; ++f) { s[f][r] = sacc[f][r] * scale; mx = fmaxf(mx, s[f][r]); }
      mx = fmaxf(mx, __shfl_xor(mx, 1));
      mx = fmaxf(mx, __shfl_xor(mx, 2));
      mx = fmaxf(mx, __shfl_xor(mx, 4));
      mx = fmaxf(mx, __shfl_xor(mx, 8));
      float mn = fmaxf(m_run[r], mx);
      corr[r] = __expf(m_run[r] - mn);
      m_run[r] = mn;
      float ls = 0.f;
      #pragma unroll
      for (int f = 0; f < 4; ++f) { s[f][r] = __expf(s[f][r] - mn); ls += s[f][r]; }
      ls += __shfl_xor(ls, 1); ls += __shfl_xor(ls, 2);
      ls += __shfl_xor(ls, 4); ls += __shfl_xor(ls, 8);
      l_run[r] = l_run[r] * corr[r] + ls;
    }

    // ---- write P (split) to per-wave LDS, row-keyed swizzle
    #pragma unroll
    for (int r = 0; r < 4; ++r) {
      int prow = lg * 4 + r;
      int sw = (prow & 7) << 3;
      #pragma unroll
      for (int f = 0; f < 4; ++f) {
        int col = (16 * f + lr) ^ sw;
        unsigned short ph = f2b(s[f][r]);
        Pwh[prow * 72 + col] = ph;
        Pwl[prow * 72 + col] = f2b(s[f][r] - b2f(ph));
      }
    }
    __syncthreads();   // P visible + all QK reads of K done

    // ---- rescale O
    #pragma unroll
    for (int f = 0; f < 4; ++f)
      #pragma unroll
      for (int r = 0; r < 4; ++r)
        oacc[f][r] *= corr[r];

    // ---- PV: O[16 rows][64 dv] += P . V
    #pragma unroll
    for (int ks = 0; ks < 2; ++ks) {
      int pbase = lr * 72 + ((ks * 32 + lk) ^ ((lr & 7) << 3));
      bf16x8 ph = *(const bf16x8*)&Pwh[pbase];
      bf16x8 pl = *(const bf16x8*)&Pwl[pbase];
      #pragma unroll
      for (int f = 0; f < 4; ++f) {
        int off = (f * 16 + lr) * 72 + ks * 32 + lk;
        bf16x8 vh = *(const bf16x8*)&Vh_[off];
        bf16x8 vl = *(const bf16x8*)&Vl_[off];
        MFMA(oacc[f], ph, vh);
        MFMA(oacc[f], ph, vl);
        MFMA(oacc[f], pl, vh);
      }
    }
  }

  // ---- epilogue: normalize, transpose via LDS, write out
  float rl[4];
  #pragma unroll
  for (int r = 0; r < 4; ++r) rl[r] = 1.0f / l_run[r];
  #pragma unroll
  for (int f = 0; f < 4; ++f)
    #pragma unroll
    for (int r = 0; r < 4; ++r)
      Os[(w * 16 + lg * 4 + r) * 68 + 16 * f + lr] = oacc[f][r] * rl[r];
  __syncthreads();
  for (int i = tid; i < 4096; i += 256) {
    int dd = i >> 6, r2 = i & 63;
    int r = r0 + r2;
    int c = r / 7, p = r - c * 7;
    Op[(size_t)dd * N_SEQ + (c * 14 + e * 7 + p)] = Os[r2 * 68 + dd];
  }
}

// ---------------------------------------------------------------------------
// GEMM 3 (split-bf16 MFMA)  [r8: PASS]
// ---------------------------------------------------------------------------
__global__ __launch_bounds__(256) void gemm_out(const float* __restrict__ W,
                                                const float* __restrict__ AO,
                                                const float* __restrict__ bias,
                                                float* __restrict__ Out) {
  const int b  = blockIdx.z;
  const int n0 = blockIdx.x * 128;
  const int m0 = blockIdx.y * 64;
  const float* Ab = AO + (size_t)b * INNER * N_SEQ;
  float* Ob = Out + (size_t)b * DIM * N_SEQ;
  __shared__ unsigned short Ah[64 * 40], Al[64 * 40];
  __shared__ unsigned short Bh[128 * 40], Bl[128 * 40];
  const int tid = threadIdx.x;
  const int lane = tid & 63, wid = tid >> 6;
  const int wr = wid >> 1, wc = wid & 1;
  const int lr = lane & 15, lk = (lane >> 4) * 8;

  f32x4 acc[2][4] = {};

  for (int k0 = 0; k0 < INNER; k0 += 32) {
    for (int i = tid; i < 2048; i += 256) {
      int kk = i & 31, mm = i >> 5;
      float v = W[(size_t)(m0 + mm) * INNER + k0 + kk];
      unsigned short h = f2b(v);
      Ah[mm * 40 + kk] = h; Al[mm * 40 + kk] = f2b(v - b2f(h));
    }
    for (int i = tid; i < 4096; i += 256) {
      int nn = i & 127, kk = i >> 7;
      float v = Ab[(size_t)(k0 + kk) * N_SEQ + n0 + nn];
      unsigned short h = f2b(v);
      Bh[nn * 40 + kk] = h; Bl[nn * 40 + kk] = f2b(v - b2f(h));
    }
    __syncthreads();
    bf16x8 ah[2], al[2], bh[4], bl[4];
    #pragma unroll
    for (int f = 0; f < 2; ++f) {
      int ar = (wr * 32 + f * 16 + lr) * 40 + lk;
      ah[f] = *(const bf16x8*)&Ah[ar]; al[f] = *(const bf16x8*)&Al[ar];
    }
    #pragma unroll
    for (int f = 0; f < 4; ++f) {
      int br = (wc * 64 + f * 16 + lr) * 40 + lk;
      bh[f] = *(const bf16x8*)&Bh[br]; bl[f] = *(const bf16x8*)&Bl[br];
    }
    #pragma unroll
    for (int fi = 0; fi < 2; ++fi)
      #pragma unroll
      for (int fj = 0; fj < 4; ++fj) {
        MFMA(acc[fi][fj], ah[fi], bh[fj]);
        MFMA(acc[fi][fj], ah[fi], bl[fj]);
        MFMA(acc[fi][fj], al[fi], bh[fj]);
      }
    __syncthreads();
  }
  const int crow = (lane >> 4) * 4, ccol = lane & 15;
  #pragma unroll
  for (int fi = 0; fi < 2; ++fi)
    #pragma unroll
    for (int fj = 0; fj < 4; ++fj) {
      int row = m0 + wr * 32 + fi * 16 + crow;
      int col = n0 + wc * 64 + fj * 16 + ccol;
      #pragma unroll
      for (int r = 0; r < 4; ++r)
        Ob[(size_t)(row + r) * N_SEQ + col] = acc[fi][fj][r] + bias[row + r];
    }
}

// ---------------------------------------------------------------------------
extern "C" void kernel_launch(void* const* d_in, const int* in_sizes, int n_in,
                              void* d_out, int out_size, void* d_ws, size_t ws_size,
                              hipStream_t stream) {
  const float* x     = (const float*)d_in[0];
  const float* w_q   = (const float*)d_in[1];
  const float* w_kv  = (const float*)d_in[2];
  const float* w_out = (const float*)d_in[3];
  const float* b_out = (const float*)d_in[4];
  float* out = (float*)d_out;

  float* q_buf  = (float*)d_ws;                                  // 2*512*3584
  float* kv_buf = q_buf + (size_t)BATCH * INNER * N_SEQ;         // 2*1024*512
  float* ao_buf = kv_buf + (size_t)BATCH * 2 * INNER * LG;       // 2*512*3584
  // split-bf16 K/V planes after ao_buf (+4MB; total ws use = 36MB)
  unsigned short* kprep = (unsigned short*)(ao_buf + (size_t)BATCH * INNER * N_SEQ);
  unsigned short* Kh = kprep;                     // [16][512][64]
  unsigned short* Kl = Kh + (size_t)16 * LG * 64;
  unsigned short* Vh = Kl + (size_t)16 * LG * 64; // [16][64][512]
  unsigned short* Vl = Vh + (size_t)16 * 64 * LG;

  gemm_q   <<<dim3(28, 4, 2),  256, 0, stream>>>(w_q, x, q_buf);
  gemm_kv  <<<dim3(8, 8, 8),   256, 0, stream>>>(w_kv, x, kv_buf, ao_buf);
  kv_prep  <<<dim3(8, 16),     256, 0, stream>>>(kv_buf, ao_buf, Kh, Kl, Vh, Vl);
  attn     <<<dim3(28, 32),    256, 0, stream>>>(q_buf, Kh, Kl, Vh, Vl, ao_buf);
  gemm_out <<<dim3(28, 4, 2),  256, 0, stream>>>(w_out, ao_buf, b_out, out);
}